// Round 1
// baseline (4852.714 us; speedup 1.0000x reference)
//
#include <hip/hip_runtime.h>
#include <math.h>

// ---------------- problem constants ----------------
#define B_SZ   2
#define NTOK   4097      // n = 4096 + cls
#define KLEN   4105      // n + mem_len(8)
#define DMODEL 512
#define INDIM  1024
#define NHEAD  8
#define DHEAD  64
#define MLPD   2048
#define MEMLEN 8
#define ATT_SCALE 0.125f // 1/sqrt(64)

#define FMA16(ac, a4, b4) \
    ac[0][0] += a4.x*b4.x; ac[0][1] += a4.x*b4.y; ac[0][2] += a4.x*b4.z; ac[0][3] += a4.x*b4.w; \
    ac[1][0] += a4.y*b4.x; ac[1][1] += a4.y*b4.y; ac[1][2] += a4.y*b4.z; ac[1][3] += a4.y*b4.w; \
    ac[2][0] += a4.z*b4.x; ac[2][1] += a4.z*b4.y; ac[2][2] += a4.z*b4.z; ac[2][3] += a4.z*b4.w; \
    ac[3][0] += a4.w*b4.x; ac[3][1] += a4.w*b4.y; ac[3][2] += a4.w*b4.z; ac[3][3] += a4.w*b4.w;

// ---------------- small helpers ----------------
__device__ __forceinline__ float block_reduce_sum_256(float v, float* sh) {
    #pragma unroll
    for (int m = 1; m < 64; m <<= 1) v += __shfl_xor(v, m);
    const int w = threadIdx.x >> 6;
    if ((threadIdx.x & 63) == 0) sh[w] = v;
    __syncthreads();
    float r = sh[0] + sh[1] + sh[2] + sh[3];
    __syncthreads();
    return r;
}

// ---------------- pos emb ----------------
__global__ void k_pos(float* __restrict__ pos) {
    const int p = blockIdx.x;          // 0..KLEN-1
    const int j = threadIdx.x;         // 0..255
    const float position = (float)(KLEN - 1 - p);
    const float inv_freq = 1.0f / powf(10000.0f, (float)j / 256.0f);
    const float x = position * inv_freq;
    pos[(long)p * DMODEL + j]       = sinf(x);
    pos[(long)p * DMODEL + 256 + j] = cosf(x);
}

// ---------------- cls token ----------------
__global__ void k_cls(const float* __restrict__ cls, float* __restrict__ x) {
    const int b = blockIdx.x;
    x[(long)b * NTOK * DMODEL + threadIdx.x] = cls[threadIdx.x];
}

// ---------------- generic tiled GEMM: C[M,N] (+)= A[M,K] @ W[K,N] + epi ----------------
enum { EPI_NONE = 0, EPI_BIAS_RELU = 1, EPI_BIAS_GELU = 2, EPI_BIAS_RES = 3 };

template <int EPI>
__global__ __launch_bounds__(256)
void k_gemm(const float* __restrict__ A, const float* __restrict__ W,
            const float* __restrict__ bias, float* __restrict__ C,
            int M, int K, int N, long sAb, long sCb)
{
    __shared__ float As[16][68];   // [k][m] transposed, padded for float4 reads
    __shared__ float Bs[16][64];   // [k][n]
    const int t  = threadIdx.x;
    const int tx = t & 15, ty = t >> 4;
    const long bm = (long)blockIdx.y * 64, bn = (long)blockIdx.x * 64;
    A += (long)blockIdx.z * sAb;
    C += (long)blockIdx.z * sCb;

    const int arow = t >> 2;          // 0..63
    const int acol = (t & 3) * 4;     // 0,4,8,12
    const int brow = t >> 4;          // 0..15
    const int bcol = (t & 15) * 4;    // 0..60
    const bool a_ok = (bm + arow) < M;
    const float* Aptr = A + (bm + arow) * (long)K + acol;
    const float* Wptr = W + (long)brow * N + bn + bcol;

    float acc[4][4] = {};
    for (int k0 = 0; k0 < K; k0 += 16) {
        float4 av = make_float4(0.f, 0.f, 0.f, 0.f);
        if (a_ok) av = *reinterpret_cast<const float4*>(Aptr + k0);
        const float4 bv = *reinterpret_cast<const float4*>(Wptr + (long)k0 * N);
        __syncthreads();
        As[acol + 0][arow] = av.x;
        As[acol + 1][arow] = av.y;
        As[acol + 2][arow] = av.z;
        As[acol + 3][arow] = av.w;
        *reinterpret_cast<float4*>(&Bs[brow][bcol]) = bv;
        __syncthreads();
        #pragma unroll
        for (int k = 0; k < 16; ++k) {
            const float4 a4 = *reinterpret_cast<const float4*>(&As[k][ty * 4]);
            const float4 b4 = *reinterpret_cast<const float4*>(&Bs[k][tx * 4]);
            FMA16(acc, a4, b4);
        }
    }

    #pragma unroll
    for (int i = 0; i < 4; ++i) {
        const long m_g = bm + ty * 4 + i;
        if (m_g < M) {
            #pragma unroll
            for (int j = 0; j < 4; ++j) {
                const long n_g = bn + tx * 4 + j;
                float r = acc[i][j];
                if (EPI != EPI_NONE) r += bias[n_g];
                if (EPI == EPI_BIAS_RELU) r = fmaxf(r, 0.f);
                if (EPI == EPI_BIAS_GELU) r = 0.5f * r * (1.f + erff(r * 0.70710678118654752f));
                if (EPI == EPI_BIAS_RES) C[m_g * N + n_g] += r;
                else                     C[m_g * N + n_g] = r;
            }
        }
    }
}

// ---------------- LayerNorm over rows of 512 ----------------
__global__ __launch_bounds__(256)
void k_ln(const float* __restrict__ x, float* __restrict__ y,
          const float* __restrict__ g, const float* __restrict__ b)
{
    __shared__ float sh[4];
    const long row = blockIdx.x;
    const float* xr = x + row * DMODEL;
    const int t = threadIdx.x;
    const float v0 = xr[t], v1 = xr[t + 256];
    const float s  = block_reduce_sum_256(v0 + v1, sh);
    const float s2 = block_reduce_sum_256(v0 * v0 + v1 * v1, sh);
    const float mu = s * (1.f / DMODEL);
    const float var = s2 * (1.f / DMODEL) - mu * mu;
    const float rs = rsqrtf(var + 1e-5f);
    y[row * DMODEL + t]       = (v0 - mu) * rs * g[t] + b[t];
    y[row * DMODEL + t + 256] = (v1 - mu) * rs * g[t + 256] + b[t + 256];
}

// ---------------- build K/V (concat mems, add pos emb) ----------------
__global__ void k_build_kv(const float* __restrict__ qkv, const float* __restrict__ mems,
                           const float* __restrict__ pos, float* __restrict__ kf,
                           float* __restrict__ vf, int layer)
{
    const int j = blockIdx.x;   // 0..KLEN-1
    const int b = blockIdx.y;
    const int d = threadIdx.x * 2;
    float2 kv, vv;
    if (j < NTOK) {
        const float* base = qkv + ((long)b * NTOK + j) * 1536;
        kv = *reinterpret_cast<const float2*>(base + 512 + d);
        vv = *reinterpret_cast<const float2*>(base + 1024 + d);
    } else {
        const float* mb = mems + (((long)layer * B_SZ + b) * MEMLEN + (j - NTOK)) * DMODEL + d;
        kv = *reinterpret_cast<const float2*>(mb);
        vv = kv;
    }
    const float2 pe = *reinterpret_cast<const float2*>(pos + (long)j * DMODEL + d);
    kv.x += pe.x; kv.y += pe.y;
    vv.x += pe.x; vv.y += pe.y;
    *reinterpret_cast<float2*>(kf + ((long)b * KLEN + j) * DMODEL + d) = kv;
    *reinterpret_cast<float2*>(vf + ((long)b * KLEN + j) * DMODEL + d) = vv;
}

// ---------------- flash attention: 64-query tile per block ----------------
__global__ __launch_bounds__(256)
void k_attn(const float* __restrict__ qkv, const float* __restrict__ kf,
            const float* __restrict__ vf, float* __restrict__ outp)
{
    __shared__ float Qs[64][68];   // [d][row]
    __shared__ float Ks[64][68];   // [d][col]
    __shared__ float Ps[64][68];   // [col][row]
    __shared__ float Vs[64][68];   // [col][d]
    const int t  = threadIdx.x;
    const int tx = t & 15, ty = t >> 4;
    const int qb = blockIdx.x * 64;
    const int h  = blockIdx.y;
    const int b  = blockIdx.z;

    #pragma unroll
    for (int rep = 0; rep < 4; ++rep) {
        const int idx = t + rep * 256;
        const int r = idx >> 4;
        const int d = (idx & 15) * 4;
        float4 v = make_float4(0.f, 0.f, 0.f, 0.f);
        const int qg = qb + r;
        if (qg < NTOK)
            v = *reinterpret_cast<const float4*>(qkv + ((long)b * NTOK + qg) * 1536 + h * 64 + d);
        Qs[d + 0][r] = v.x; Qs[d + 1][r] = v.y; Qs[d + 2][r] = v.z; Qs[d + 3][r] = v.w;
    }

    float o[4][4] = {};
    float m_run[4] = {-INFINITY, -INFINITY, -INFINITY, -INFINITY};
    float l_run[4] = {};

    const int NKT = (KLEN + 63) / 64;   // 65
    for (int kt = 0; kt < NKT; ++kt) {
        const int kb = kt * 64;
        __syncthreads();   // prev tile's P-GEMM done -> safe to overwrite Ks/Vs/Ps
        #pragma unroll
        for (int rep = 0; rep < 4; ++rep) {
            const int idx = t + rep * 256;
            const int c = idx >> 4;
            const int d = (idx & 15) * 4;
            const int jg = kb + c;
            float4 kv = make_float4(0.f, 0.f, 0.f, 0.f);
            float4 vv = make_float4(0.f, 0.f, 0.f, 0.f);
            if (jg < KLEN) {
                kv = *reinterpret_cast<const float4*>(kf + ((long)b * KLEN + jg) * DMODEL + h * 64 + d);
                vv = *reinterpret_cast<const float4*>(vf + ((long)b * KLEN + jg) * DMODEL + h * 64 + d);
            }
            Ks[d + 0][c] = kv.x; Ks[d + 1][c] = kv.y; Ks[d + 2][c] = kv.z; Ks[d + 3][c] = kv.w;
            *reinterpret_cast<float4*>(&Vs[c][d]) = vv;
        }
        __syncthreads();

        // S = Q @ K^T  (dot over d=64)
        float s[4][4] = {};
        #pragma unroll 16
        for (int d = 0; d < 64; ++d) {
            const float4 a4 = *reinterpret_cast<const float4*>(&Qs[d][ty * 4]);
            const float4 b4 = *reinterpret_cast<const float4*>(&Ks[d][tx * 4]);
            FMA16(s, a4, b4);
        }

        // online softmax (rows ty*4+i, cols distributed over tx)
        #pragma unroll
        for (int i = 0; i < 4; ++i) {
            #pragma unroll
            for (int j = 0; j < 4; ++j) {
                const int cg = kb + tx * 4 + j;
                s[i][j] = (cg < KLEN) ? s[i][j] * ATT_SCALE : -INFINITY;
            }
            float mx = fmaxf(fmaxf(s[i][0], s[i][1]), fmaxf(s[i][2], s[i][3]));
            mx = fmaxf(mx, __shfl_xor(mx, 1));
            mx = fmaxf(mx, __shfl_xor(mx, 2));
            mx = fmaxf(mx, __shfl_xor(mx, 4));
            mx = fmaxf(mx, __shfl_xor(mx, 8));
            const float mnew = fmaxf(m_run[i], mx);
            const float alpha = expf(m_run[i] - mnew);   // first tile: exp(-inf)=0
            float l = 0.f;
            #pragma unroll
            for (int j = 0; j < 4; ++j) {
                const float p = expf(s[i][j] - mnew);
                s[i][j] = p;
                l += p;
            }
            l += __shfl_xor(l, 1);
            l += __shfl_xor(l, 2);
            l += __shfl_xor(l, 4);
            l += __shfl_xor(l, 8);
            l_run[i] = l_run[i] * alpha + l;
            m_run[i] = mnew;
            o[i][0] *= alpha; o[i][1] *= alpha; o[i][2] *= alpha; o[i][3] *= alpha;
        }

        // stash P transposed
        #pragma unroll
        for (int i = 0; i < 4; ++i)
            #pragma unroll
            for (int j = 0; j < 4; ++j)
                Ps[tx * 4 + j][ty * 4 + i] = s[i][j];
        __syncthreads();

        // O += P @ V
        #pragma unroll 16
        for (int c = 0; c < 64; ++c) {
            const float4 a4 = *reinterpret_cast<const float4*>(&Ps[c][ty * 4]);
            const float4 b4 = *reinterpret_cast<const float4*>(&Vs[c][tx * 4]);
            FMA16(o, a4, b4);
        }
    }

    #pragma unroll
    for (int i = 0; i < 4; ++i) {
        const int rg = qb + ty * 4 + i;
        if (rg < NTOK) {
            const float inv = 1.f / l_run[i];
            float* op = outp + ((long)b * NTOK + rg) * DMODEL + h * 64 + tx * 4;
            op[0] = o[i][0] * inv;
            op[1] = o[i][1] * inv;
            op[2] = o[i][2] * inv;
            op[3] = o[i][3] * inv;
        }
    }
}

// ---------------- final LN + 2-class head on cls row ----------------
__global__ __launch_bounds__(256)
void k_final(const float* __restrict__ x, const float* __restrict__ g,
             const float* __restrict__ bb, const float* __restrict__ w2,
             const float* __restrict__ b2, float* __restrict__ out)
{
    __shared__ float sh[4];
    const int b = blockIdx.x;
    const float* xr = x + (long)b * NTOK * DMODEL;
    const int t = threadIdx.x;
    const float v0 = xr[t], v1 = xr[t + 256];
    const float s  = block_reduce_sum_256(v0 + v1, sh);
    const float s2 = block_reduce_sum_256(v0 * v0 + v1 * v1, sh);
    const float mu = s * (1.f / DMODEL);
    const float var = s2 * (1.f / DMODEL) - mu * mu;
    const float rs = rsqrtf(var + 1e-5f);
    const float n0 = (v0 - mu) * rs * g[t] + bb[t];
    const float n1 = (v1 - mu) * rs * g[t + 256] + bb[t + 256];
    const float p0 = block_reduce_sum_256(n0 * w2[t * 2 + 0] + n1 * w2[(t + 256) * 2 + 0], sh);
    const float p1 = block_reduce_sum_256(n0 * w2[t * 2 + 1] + n1 * w2[(t + 256) * 2 + 1], sh);
    if (t == 0) {
        out[b * 2 + 0] = p0 + b2[0];
        out[b * 2 + 1] = p1 + b2[1];
    }
}

// ---------------- host orchestration ----------------
extern "C" void kernel_launch(void* const* d_in, const int* in_sizes, int n_in,
                              void* d_out, int out_size, void* d_ws, size_t ws_size,
                              hipStream_t stream)
{
    const float* data    = (const float*)d_in[0];
    const float* mems    = (const float*)d_in[1];
    const float* fc1_w   = (const float*)d_in[2];
    const float* fc1_b   = (const float*)d_in[3];
    const float* cls     = (const float*)d_in[4];
    const float* ln1_g   = (const float*)d_in[5];
    const float* ln1_b   = (const float*)d_in[6];
    const float* qkv_w   = (const float*)d_in[7];
    const float* out_w   = (const float*)d_in[8];
    const float* out_b   = (const float*)d_in[9];
    const float* ln2_g   = (const float*)d_in[10];
    const float* ln2_b   = (const float*)d_in[11];
    const float* ff_w1   = (const float*)d_in[12];
    const float* ff_b1   = (const float*)d_in[13];
    const float* ff_w2   = (const float*)d_in[14];
    const float* ff_b2   = (const float*)d_in[15];
    const float* normf_g = (const float*)d_in[16];
    const float* normf_b = (const float*)d_in[17];
    const float* fc2_w   = (const float*)d_in[18];
    const float* fc2_b   = (const float*)d_in[19];
    float* out = (float*)d_out;

    // workspace layout (floats)
    const long size_x   = (long)B_SZ * NTOK * DMODEL;       //  4,195,328
    const long size_pos = (long)KLEN * DMODEL;              //  2,101,760
    float* ws  = (float*)d_ws;
    float* x   = ws;                                        // [B, NTOK, 512]
    float* xa  = ws + size_x;                               // LN out / attn out
    float* pos = ws + 2 * size_x;                           // [KLEN, 512]
    float* S   = pos + size_pos;                            // scratch union
    float* qkv = S;                                         // [B*NTOK, 1536]
    float* kf  = S + (long)(B_SZ * NTOK) * 1536;            // [B, KLEN, 512]
    float* vf  = kf + (long)B_SZ * KLEN * DMODEL;           // [B, KLEN, 512]
    float* ff1 = S;                                         // [B*NTOK, 2048] (overlays qkv/kf)

    const int MROWS = B_SZ * NTOK;                          // 8194
    const int MT = (MROWS + 63) / 64;                       // 129

    k_pos<<<dim3(KLEN), dim3(256), 0, stream>>>(pos);
    k_cls<<<dim3(B_SZ), dim3(512), 0, stream>>>(cls, x);
    // fc1 + ReLU  -> x rows 1..4096 per batch
    k_gemm<EPI_BIAS_RELU><<<dim3(DMODEL / 64, 4096 / 64, B_SZ), dim3(256), 0, stream>>>(
        data, fc1_w, fc1_b, x + DMODEL, 4096, INDIM, DMODEL,
        (long)4096 * INDIM, (long)NTOK * DMODEL);

    for (int l = 0; l < 2; ++l) {
        k_ln<<<dim3(MROWS), dim3(256), 0, stream>>>(x, xa, ln1_g + l * DMODEL, ln1_b + l * DMODEL);
        k_gemm<EPI_NONE><<<dim3(1536 / 64, MT, 1), dim3(256), 0, stream>>>(
            xa, qkv_w + (long)l * DMODEL * 1536, nullptr, qkv, MROWS, DMODEL, 1536, 0, 0);
        k_build_kv<<<dim3(KLEN, B_SZ), dim3(256), 0, stream>>>(qkv, mems, pos, kf, vf, l);
        k_attn<<<dim3((NTOK + 63) / 64, NHEAD, B_SZ), dim3(256), 0, stream>>>(qkv, kf, vf, xa);
        k_gemm<EPI_BIAS_RES><<<dim3(DMODEL / 64, MT, 1), dim3(256), 0, stream>>>(
            xa, out_w + (long)l * DMODEL * DMODEL, out_b + l * DMODEL, x, MROWS, DMODEL, DMODEL, 0, 0);
        k_ln<<<dim3(MROWS), dim3(256), 0, stream>>>(x, xa, ln2_g + l * DMODEL, ln2_b + l * DMODEL);
        k_gemm<EPI_BIAS_GELU><<<dim3(MLPD / 64, MT, 1), dim3(256), 0, stream>>>(
            xa, ff_w1 + (long)l * DMODEL * MLPD, ff_b1 + l * MLPD, ff1, MROWS, DMODEL, MLPD, 0, 0);
        k_gemm<EPI_BIAS_RES><<<dim3(DMODEL / 64, MT, 1), dim3(256), 0, stream>>>(
            ff1, ff_w2 + (long)l * MLPD * DMODEL, ff_b2 + l * DMODEL, x, MROWS, MLPD, DMODEL, 0, 0);
    }

    k_final<<<dim3(B_SZ), dim3(256), 0, stream>>>(x, normf_g, normf_b, fc2_w, fc2_b, out);
}

// Round 3
// 2489.914 us; speedup vs baseline: 1.9489x; 1.9489x over previous
//
#include <hip/hip_runtime.h>
#include <hip/hip_bf16.h>
#include <math.h>

// ---------------- problem constants ----------------
#define B_SZ   2
#define NTOK   4097      // n = 4096 + cls
#define KLEN   4105      // n + mem_len(8)
#define KLEN_PAD 4160    // 65 * 64
#define DMODEL 512
#define INDIM  1024
#define NHEAD  8
#define DHEAD  64
#define MLPD   2048
#define MEMLEN 8
#define ATT_SCALE 0.125f // 1/sqrt(64)
#define NEG_BIG  -1.0e30f

typedef short bf16x8 __attribute__((ext_vector_type(8)));
typedef float f32x4  __attribute__((ext_vector_type(4)));

#define FMA16(ac, a4, b4) \
    ac[0][0] += a4.x*b4.x; ac[0][1] += a4.x*b4.y; ac[0][2] += a4.x*b4.z; ac[0][3] += a4.x*b4.w; \
    ac[1][0] += a4.y*b4.x; ac[1][1] += a4.y*b4.y; ac[1][2] += a4.y*b4.z; ac[1][3] += a4.y*b4.w; \
    ac[2][0] += a4.z*b4.x; ac[2][1] += a4.z*b4.y; ac[2][2] += a4.z*b4.z; ac[2][3] += a4.z*b4.w; \
    ac[3][0] += a4.w*b4.x; ac[3][1] += a4.w*b4.y; ac[3][2] += a4.w*b4.z; ac[3][3] += a4.w*b4.w;

__device__ __forceinline__ unsigned short f2bf(float f) {
    union { float f; unsigned u; } v; v.f = f;
    const unsigned r = v.u + 0x7fff + ((v.u >> 16) & 1);   // RTNE
    return (unsigned short)(r >> 16);
}

// ---------------- small helpers ----------------
__device__ __forceinline__ float block_reduce_sum_256(float v, float* sh) {
    #pragma unroll
    for (int m = 1; m < 64; m <<= 1) v += __shfl_xor(v, m);
    const int w = threadIdx.x >> 6;
    if ((threadIdx.x & 63) == 0) sh[w] = v;
    __syncthreads();
    float r = sh[0] + sh[1] + sh[2] + sh[3];
    __syncthreads();
    return r;
}

// ---------------- pos emb ----------------
__global__ void k_pos(float* __restrict__ pos) {
    const int p = blockIdx.x;          // 0..KLEN-1
    const int j = threadIdx.x;         // 0..255
    const float position = (float)(KLEN - 1 - p);
    const float inv_freq = 1.0f / powf(10000.0f, (float)j / 256.0f);
    const float x = position * inv_freq;
    pos[(long)p * DMODEL + j]       = sinf(x);
    pos[(long)p * DMODEL + 256 + j] = cosf(x);
}

// ---------------- cls token ----------------
__global__ void k_cls(const float* __restrict__ cls, float* __restrict__ x) {
    const int b = blockIdx.x;
    x[(long)b * NTOK * DMODEL + threadIdx.x] = cls[threadIdx.x];
}

// ---------------- generic tiled GEMM (fp32): C[M,N] (+)= A[M,K] @ W[K,N] + epi ----------------
enum { EPI_NONE = 0, EPI_BIAS_RELU = 1, EPI_BIAS_GELU = 2, EPI_BIAS_RES = 3 };

template <int EPI>
__global__ __launch_bounds__(256)
void k_gemm(const float* __restrict__ A, const float* __restrict__ W,
            const float* __restrict__ bias, float* __restrict__ C,
            int M, int K, int N, long sAb, long sCb)
{
    __shared__ float As[16][68];   // [k][m] transposed, padded
    __shared__ float Bs[16][64];   // [k][n]
    const int t  = threadIdx.x;
    const int tx = t & 15, ty = t >> 4;
    const long bm = (long)blockIdx.y * 64, bn = (long)blockIdx.x * 64;
    A += (long)blockIdx.z * sAb;
    C += (long)blockIdx.z * sCb;

    const int arow = t >> 2;
    const int acol = (t & 3) * 4;
    const int brow = t >> 4;
    const int bcol = (t & 15) * 4;
    const bool a_ok = (bm + arow) < M;
    const float* Aptr = A + (bm + arow) * (long)K + acol;
    const float* Wptr = W + (long)brow * N + bn + bcol;

    float acc[4][4] = {};
    for (int k0 = 0; k0 < K; k0 += 16) {
        float4 av = make_float4(0.f, 0.f, 0.f, 0.f);
        if (a_ok) av = *reinterpret_cast<const float4*>(Aptr + k0);
        const float4 bv = *reinterpret_cast<const float4*>(Wptr + (long)k0 * N);
        __syncthreads();
        As[acol + 0][arow] = av.x;
        As[acol + 1][arow] = av.y;
        As[acol + 2][arow] = av.z;
        As[acol + 3][arow] = av.w;
        *reinterpret_cast<float4*>(&Bs[brow][bcol]) = bv;
        __syncthreads();
        #pragma unroll
        for (int k = 0; k < 16; ++k) {
            const float4 a4 = *reinterpret_cast<const float4*>(&As[k][ty * 4]);
            const float4 b4 = *reinterpret_cast<const float4*>(&Bs[k][tx * 4]);
            FMA16(acc, a4, b4);
        }
    }

    #pragma unroll
    for (int i = 0; i < 4; ++i) {
        const long m_g = bm + ty * 4 + i;
        if (m_g < M) {
            #pragma unroll
            for (int j = 0; j < 4; ++j) {
                const long n_g = bn + tx * 4 + j;
                float r = acc[i][j];
                if (EPI != EPI_NONE) r += bias[n_g];
                if (EPI == EPI_BIAS_RELU) r = fmaxf(r, 0.f);
                if (EPI == EPI_BIAS_GELU) r = 0.5f * r * (1.f + erff(r * 0.70710678118654752f));
                if (EPI == EPI_BIAS_RES) C[m_g * N + n_g] += r;
                else                     C[m_g * N + n_g] = r;
            }
        }
    }
}

// ---------------- LayerNorm over rows of 512 ----------------
__global__ __launch_bounds__(256)
void k_ln(const float* __restrict__ x, float* __restrict__ y,
          const float* __restrict__ g, const float* __restrict__ b)
{
    __shared__ float sh[4];
    const long row = blockIdx.x;
    const float* xr = x + row * DMODEL;
    const int t = threadIdx.x;
    const float v0 = xr[t], v1 = xr[t + 256];
    const float s  = block_reduce_sum_256(v0 + v1, sh);
    const float s2 = block_reduce_sum_256(v0 * v0 + v1 * v1, sh);
    const float mu = s * (1.f / DMODEL);
    const float var = s2 * (1.f / DMODEL) - mu * mu;
    const float rs = rsqrtf(var + 1e-5f);
    y[row * DMODEL + t]       = (v0 - mu) * rs * g[t] + b[t];
    y[row * DMODEL + t + 256] = (v1 - mu) * rs * g[t + 256] + b[t + 256];
}

// ---------------- build bf16 K (row-major) and V (transposed per head) ----------------
__global__ __launch_bounds__(256)
void k_build_kv(const float* __restrict__ qkv, const float* __restrict__ mems,
                const float* __restrict__ pos, unsigned short* __restrict__ kf,
                unsigned short* __restrict__ vt, int layer)
{
    const int jb = blockIdx.x * 64;
    const int b  = blockIdx.y;
    const int t  = threadIdx.x;

    if (blockIdx.z == 0) {
        // K: [b][klen][512] bf16, coalesced row writes
        for (int r = 0; r < 64; ++r) {
            const int j = jb + r;
            if (j >= KLEN) break;
            #pragma unroll
            for (int half = 0; half < 2; ++half) {
                const int d = t + half * 256;
                float val;
                if (j < NTOK) val = qkv[((long)b * NTOK + j) * 1536 + 512 + d];
                else          val = mems[(((long)layer * B_SZ + b) * MEMLEN + (j - NTOK)) * DMODEL + d];
                val += pos[(long)j * DMODEL + d];
                kf[((long)b * KLEN + j) * DMODEL + d] = f2bf(val);
            }
        }
    } else {
        // V transposed: [b*8+h][d=64][KLEN_PAD] bf16; tail keys [KLEN,KLEN_PAD) zeroed
        const int j = jb + (t & 63);
        if (j < KLEN_PAD) {
            const int dbase = (t >> 6) * 128;
            for (int dd = 0; dd < 128; ++dd) {
                const int d = dbase + dd;
                float val = 0.f;
                if (j < NTOK)
                    val = qkv[((long)b * NTOK + j) * 1536 + 1024 + d] + pos[(long)j * DMODEL + d];
                else if (j < KLEN)
                    val = mems[(((long)layer * B_SZ + b) * MEMLEN + (j - NTOK)) * DMODEL + d]
                        + pos[(long)j * DMODEL + d];
                vt[(((long)b * NHEAD + (d >> 6)) * 64 + (d & 63)) * (long)KLEN_PAD + j] = f2bf(val);
            }
        }
    }
}

// ---------------- MFMA flash attention: 64-query tile, 4 waves ----------------
#define LDSP 72   // padded LDS row length in ushorts (144 B)

__global__ __launch_bounds__(256)
void k_attn_mfma(const float* __restrict__ qkv,
                 const unsigned short* __restrict__ kf,
                 const unsigned short* __restrict__ vt,
                 float* __restrict__ outp)
{
    __shared__ unsigned short QPs[64][LDSP];  // Q at start, then reused as P
    __shared__ unsigned short Ks [64][LDSP];  // keys x d
    __shared__ unsigned short Vts[64][LDSP];  // d x keys

    const int t    = threadIdx.x;
    const int lane = t & 63;
    const int w    = t >> 6;        // wave 0..3 -> rows w*16..w*16+15
    const int l15  = lane & 15;
    const int lhi  = lane >> 4;     // 0..3
    const int qb   = blockIdx.x * 64;
    const int h    = blockIdx.y;
    const int b    = blockIdx.z;

    // ---- stage Q (fp32 -> bf16) ----
    {
        const int r  = t >> 2;
        const int c0 = (t & 3) * 16;
        const int qg = qb + r;
        float4 f[4];
        if (qg < NTOK) {
            const float* src = qkv + ((long)b * NTOK + qg) * 1536 + h * 64 + c0;
            f[0] = ((const float4*)src)[0]; f[1] = ((const float4*)src)[1];
            f[2] = ((const float4*)src)[2]; f[3] = ((const float4*)src)[3];
        } else {
            f[0] = f[1] = f[2] = f[3] = make_float4(0.f, 0.f, 0.f, 0.f);
        }
        #pragma unroll
        for (int i = 0; i < 4; ++i) {
            QPs[r][c0 + i*4 + 0] = f2bf(f[i].x);
            QPs[r][c0 + i*4 + 1] = f2bf(f[i].y);
            QPs[r][c0 + i*4 + 2] = f2bf(f[i].z);
            QPs[r][c0 + i*4 + 3] = f2bf(f[i].w);
        }
    }
    __syncthreads();
    bf16x8 q_frag[2];
    #pragma unroll
    for (int ks = 0; ks < 2; ++ks)
        q_frag[ks] = *(const bf16x8*)&QPs[w * 16 + l15][ks * 32 + lhi * 8];

    f32x4 o_frag[4] = {};
    float m_run[4] = {NEG_BIG, NEG_BIG, NEG_BIG, NEG_BIG};
    float l_run[4] = {0.f, 0.f, 0.f, 0.f};

    const unsigned short* kbase = kf + (long)b * KLEN * DMODEL + h * 64;
    const unsigned short* vbase = vt + ((long)b * NHEAD + h) * 64 * (long)KLEN_PAD;

    for (int kt = 0; kt < 65; ++kt) {
        const int kb = kt * 64;
        __syncthreads();   // prev tile's MFMA reads done
        // ---- stage K tile [key][d] and Vt tile [d][key] ----
        {
            const int r = t >> 2;
            const int jg = kb + r;
            #pragma unroll
            for (int cc = 0; cc < 2; ++cc) {
                const int c8 = (t & 3) * 2 + cc;   // 0..7
                uint4 kv = make_uint4(0u, 0u, 0u, 0u);
                if (jg < KLEN) kv = *(const uint4*)(kbase + (long)jg * DMODEL + c8 * 8);
                *(uint4*)&Ks[r][c8 * 8] = kv;
                const uint4 vv = *(const uint4*)(vbase + (long)r * KLEN_PAD + kb + c8 * 8);
                *(uint4*)&Vts[r][c8 * 8] = vv;
            }
        }
        __syncthreads();

        // ---- S = Q @ K^T ----
        f32x4 s_frag[4];
        #pragma unroll
        for (int n = 0; n < 4; ++n) {
            f32x4 acc = {0.f, 0.f, 0.f, 0.f};
            #pragma unroll
            for (int ks = 0; ks < 2; ++ks) {
                const bf16x8 kfr = *(const bf16x8*)&Ks[n * 16 + l15][ks * 32 + lhi * 8];
                acc = __builtin_amdgcn_mfma_f32_16x16x32_bf16(q_frag[ks], kfr, acc, 0, 0, 0);
            }
            s_frag[n] = acc;
        }

        // ---- online softmax on C-layout (row = lhi*4+i, col = n*16+l15) ----
        #pragma unroll
        for (int i = 0; i < 4; ++i) {
            float sv[4];
            #pragma unroll
            for (int n = 0; n < 4; ++n) {
                const int cg = kb + n * 16 + l15;
                sv[n] = (cg < KLEN) ? s_frag[n][i] * ATT_SCALE : NEG_BIG;
            }
            float mx = fmaxf(fmaxf(sv[0], sv[1]), fmaxf(sv[2], sv[3]));
            mx = fmaxf(mx, __shfl_xor(mx, 1));
            mx = fmaxf(mx, __shfl_xor(mx, 2));
            mx = fmaxf(mx, __shfl_xor(mx, 4));
            mx = fmaxf(mx, __shfl_xor(mx, 8));
            const float mnew  = fmaxf(m_run[i], mx);
            const float alpha = __expf(m_run[i] - mnew);   // finite - finite, <= 0
            float lsum = 0.f;
            unsigned short pb[4];
            #pragma unroll
            for (int n = 0; n < 4; ++n) {
                const float p = __expf(sv[n] - mnew);
                lsum += p;
                pb[n] = f2bf(p);
            }
            lsum += __shfl_xor(lsum, 1);
            lsum += __shfl_xor(lsum, 2);
            lsum += __shfl_xor(lsum, 4);
            lsum += __shfl_xor(lsum, 8);
            l_run[i] = l_run[i] * alpha + lsum;
            m_run[i] = mnew;
            #pragma unroll
            for (int n = 0; n < 4; ++n) {
                o_frag[n][i] *= alpha;
                QPs[w * 16 + lhi * 4 + i][n * 16 + l15] = pb[n];   // P, wave-private strip
            }
        }
        __syncthreads();   // P visible (belt-and-braces handoff)

        // ---- O += P @ V ----
        #pragma unroll
        for (int n = 0; n < 4; ++n) {
            #pragma unroll
            for (int ks = 0; ks < 2; ++ks) {
                const bf16x8 pa = *(const bf16x8*)&QPs[w * 16 + l15][ks * 32 + lhi * 8];
                const bf16x8 vb = *(const bf16x8*)&Vts[n * 16 + l15][ks * 32 + lhi * 8];
                o_frag[n] = __builtin_amdgcn_mfma_f32_16x16x32_bf16(pa, vb, o_frag[n], 0, 0, 0);
            }
        }
    }

    // ---- epilogue ----
    #pragma unroll
    for (int i = 0; i < 4; ++i) {
        const int rg = qb + w * 16 + lhi * 4 + i;
        if (rg < NTOK) {
            const float inv = 1.f / l_run[i];
            float* op = outp + ((long)b * NTOK + rg) * DMODEL + h * 64 + l15;
            #pragma unroll
            for (int n = 0; n < 4; ++n) op[n * 16] = o_frag[n][i] * inv;
        }
    }
}

// ---------------- final LN + 2-class head on cls row ----------------
__global__ __launch_bounds__(256)
void k_final(const float* __restrict__ x, const float* __restrict__ g,
             const float* __restrict__ bb, const float* __restrict__ w2,
             const float* __restrict__ b2, float* __restrict__ out)
{
    __shared__ float sh[4];
    const int b = blockIdx.x;
    const float* xr = x + (long)b * NTOK * DMODEL;
    const int t = threadIdx.x;
    const float v0 = xr[t], v1 = xr[t + 256];
    const float s  = block_reduce_sum_256(v0 + v1, sh);
    const float s2 = block_reduce_sum_256(v0 * v0 + v1 * v1, sh);
    const float mu = s * (1.f / DMODEL);
    const float var = s2 * (1.f / DMODEL) - mu * mu;
    const float rs = rsqrtf(var + 1e-5f);
    const float n0 = (v0 - mu) * rs * g[t] + bb[t];
    const float n1 = (v1 - mu) * rs * g[t + 256] + bb[t + 256];
    const float p0 = block_reduce_sum_256(n0 * w2[t * 2 + 0] + n1 * w2[(t + 256) * 2 + 0], sh);
    const float p1 = block_reduce_sum_256(n0 * w2[t * 2 + 1] + n1 * w2[(t + 256) * 2 + 1], sh);
    if (t == 0) {
        out[b * 2 + 0] = p0 + b2[0];
        out[b * 2 + 1] = p1 + b2[1];
    }
}

// ---------------- host orchestration ----------------
extern "C" void kernel_launch(void* const* d_in, const int* in_sizes, int n_in,
                              void* d_out, int out_size, void* d_ws, size_t ws_size,
                              hipStream_t stream)
{
    const float* data    = (const float*)d_in[0];
    const float* mems    = (const float*)d_in[1];
    const float* fc1_w   = (const float*)d_in[2];
    const float* fc1_b   = (const float*)d_in[3];
    const float* cls     = (const float*)d_in[4];
    const float* ln1_g   = (const float*)d_in[5];
    const float* ln1_b   = (const float*)d_in[6];
    const float* qkv_w   = (const float*)d_in[7];
    const float* out_w   = (const float*)d_in[8];
    const float* out_b   = (const float*)d_in[9];
    const float* ln2_g   = (const float*)d_in[10];
    const float* ln2_b   = (const float*)d_in[11];
    const float* ff_w1   = (const float*)d_in[12];
    const float* ff_b1   = (const float*)d_in[13];
    const float* ff_w2   = (const float*)d_in[14];
    const float* ff_b2   = (const float*)d_in[15];
    const float* normf_g = (const float*)d_in[16];
    const float* normf_b = (const float*)d_in[17];
    const float* fc2_w   = (const float*)d_in[18];
    const float* fc2_b   = (const float*)d_in[19];
    float* out = (float*)d_out;

    // workspace layout (float units)
    const long size_x   = (long)B_SZ * NTOK * DMODEL;       // 4,195,328
    const long size_pos = (long)KLEN * DMODEL;              // 2,101,760
    const long size_qkv = (long)B_SZ * NTOK * 1536;         // 12,585,984
    float* ws  = (float*)d_ws;
    float* x   = ws;                                        // [B, NTOK, 512]
    float* xa  = ws + size_x;                               // LN out / attn out
    float* pos = ws + 2 * size_x;                           // [KLEN, 512]
    float* S   = pos + size_pos;                            // scratch union
    float* qkv = S;                                         // [B*NTOK, 1536] fp32
    unsigned short* kf = (unsigned short*)(S + size_qkv);   // [B, KLEN, 512] bf16
    unsigned short* vt = kf + (long)B_SZ * KLEN * DMODEL;   // [B*8, 64, KLEN_PAD] bf16
    float* ff1 = S;                                         // [B*NTOK, 2048] (overlays qkv/kf/vt)

    const int MROWS = B_SZ * NTOK;                          // 8194
    const int MT = (MROWS + 63) / 64;                       // 129

    k_pos<<<dim3(KLEN), dim3(256), 0, stream>>>(pos);
    k_cls<<<dim3(B_SZ), dim3(512), 0, stream>>>(cls, x);
    k_gemm<EPI_BIAS_RELU><<<dim3(DMODEL / 64, 4096 / 64, B_SZ), dim3(256), 0, stream>>>(
        data, fc1_w, fc1_b, x + DMODEL, 4096, INDIM, DMODEL,
        (long)4096 * INDIM, (long)NTOK * DMODEL);

    for (int l = 0; l < 2; ++l) {
        k_ln<<<dim3(MROWS), dim3(256), 0, stream>>>(x, xa, ln1_g + l * DMODEL, ln1_b + l * DMODEL);
        k_gemm<EPI_NONE><<<dim3(1536 / 64, MT, 1), dim3(256), 0, stream>>>(
            xa, qkv_w + (long)l * DMODEL * 1536, nullptr, qkv, MROWS, DMODEL, 1536, 0, 0);
        k_build_kv<<<dim3((KLEN_PAD + 63) / 64, B_SZ, 2), dim3(256), 0, stream>>>(
            qkv, mems, pos, kf, vt, l);
        k_attn_mfma<<<dim3((NTOK + 63) / 64, NHEAD, B_SZ), dim3(256), 0, stream>>>(
            qkv, kf, vt, xa);
        k_gemm<EPI_BIAS_RES><<<dim3(DMODEL / 64, MT, 1), dim3(256), 0, stream>>>(
            xa, out_w + (long)l * DMODEL * DMODEL, out_b + l * DMODEL, x, MROWS, DMODEL, DMODEL, 0, 0);
        k_ln<<<dim3(MROWS), dim3(256), 0, stream>>>(x, xa, ln2_g + l * DMODEL, ln2_b + l * DMODEL);
        k_gemm<EPI_BIAS_GELU><<<dim3(MLPD / 64, MT, 1), dim3(256), 0, stream>>>(
            xa, ff_w1 + (long)l * DMODEL * MLPD, ff_b1 + l * MLPD, ff1, MROWS, DMODEL, MLPD, 0, 0);
        k_gemm<EPI_BIAS_RES><<<dim3(DMODEL / 64, MT, 1), dim3(256), 0, stream>>>(
            ff1, ff_w2 + (long)l * MLPD * DMODEL, ff_b2 + l * DMODEL, x, MROWS, MLPD, DMODEL, 0, 0);
    }

    k_final<<<dim3(B_SZ), dim3(256), 0, stream>>>(x, normf_g, normf_b, fc2_w, fc2_b, out);
}

// Round 4
// 1271.136 us; speedup vs baseline: 3.8176x; 1.9588x over previous
//
#include <hip/hip_runtime.h>
#include <hip/hip_bf16.h>
#include <math.h>

// ---------------- problem constants ----------------
#define B_SZ   2
#define NTOK   4097      // n = 4096 + cls
#define KLEN   4105      // n + mem_len(8)
#define KLEN_PAD 4160    // 65 * 64
#define DMODEL 512
#define INDIM  1024
#define NHEAD  8
#define DHEAD  64
#define MLPD   2048
#define MEMLEN 8
#define ATT_SCALE 0.125f // 1/sqrt(64)
#define NEG_BIG  -1.0e30f

typedef unsigned short ushort_t;
typedef short bf16x8 __attribute__((ext_vector_type(8)));
typedef float f32x4  __attribute__((ext_vector_type(4)));

__device__ __forceinline__ unsigned short f2bf(float f) {
    union { float f; unsigned u; } v; v.f = f;
    const unsigned r = v.u + 0x7fff + ((v.u >> 16) & 1);   // RTNE
    return (unsigned short)(r >> 16);
}
__device__ __forceinline__ float bf2f(unsigned short u) {
    union { unsigned u; float f; } v; v.u = ((unsigned)u) << 16;
    return v.f;
}

// async global->LDS, 16B per lane; lds base must be wave-uniform
__device__ __forceinline__ void gload_lds16(const void* g, void* l) {
    __builtin_amdgcn_global_load_lds(
        (const __attribute__((address_space(1))) unsigned int*)g,
        (__attribute__((address_space(3))) unsigned int*)l, 16, 0, 0);
}

// ---------------- small helpers ----------------
__device__ __forceinline__ float block_reduce_sum_256(float v, float* sh) {
    #pragma unroll
    for (int m = 1; m < 64; m <<= 1) v += __shfl_xor(v, m);
    const int w = threadIdx.x >> 6;
    if ((threadIdx.x & 63) == 0) sh[w] = v;
    __syncthreads();
    float r = sh[0] + sh[1] + sh[2] + sh[3];
    __syncthreads();
    return r;
}

// ---------------- pos emb ----------------
__global__ void k_pos(float* __restrict__ pos) {
    const int p = blockIdx.x;
    const int j = threadIdx.x;
    const float position = (float)(KLEN - 1 - p);
    const float inv_freq = 1.0f / powf(10000.0f, (float)j / 256.0f);
    const float x = position * inv_freq;
    pos[(long)p * DMODEL + j]       = sinf(x);
    pos[(long)p * DMODEL + 256 + j] = cosf(x);
}

// ---------------- cls token ----------------
__global__ void k_cls(const float* __restrict__ cls, float* __restrict__ x) {
    const int b = blockIdx.x;
    x[(long)b * NTOK * DMODEL + threadIdx.x] = cls[threadIdx.x];
}

// ---------------- fp32 -> bf16 convert (grid-stride, float4) ----------------
__global__ __launch_bounds__(256)
void k_f2b(const float* __restrict__ in, ushort_t* __restrict__ out, long n4) {
    for (long i = blockIdx.x * 256 + threadIdx.x; i < n4; i += (long)gridDim.x * 256) {
        const float4 f = ((const float4*)in)[i];
        ushort4 u;
        u.x = f2bf(f.x); u.y = f2bf(f.y); u.z = f2bf(f.z); u.w = f2bf(f.w);
        ((ushort4*)out)[i] = u;
    }
}

// ---------------- weight fp32[K][N] -> bf16 Wt[N][K] (tiled transpose) ----------------
__global__ __launch_bounds__(256)
void k_w2bt(const float* __restrict__ W, ushort_t* __restrict__ Wt, int K, int N) {
    __shared__ float tile[64][65];
    W  += (long)blockIdx.z * K * N;
    Wt += (long)blockIdx.z * N * K;
    const int n0 = blockIdx.x * 64, k0 = blockIdx.y * 64;
    const int t = threadIdx.x;
    #pragma unroll
    for (int rep = 0; rep < 16; ++rep) {
        const int idx = rep * 256 + t;
        const int r = idx >> 6, c = idx & 63;
        tile[r][c] = W[(long)(k0 + r) * N + n0 + c];
    }
    __syncthreads();
    #pragma unroll
    for (int rep = 0; rep < 16; ++rep) {
        const int idx = rep * 256 + t;
        const int n = idx >> 6, kk = idx & 63;
        Wt[(long)(n0 + n) * K + k0 + kk] = f2bf(tile[kk][n]);
    }
}

// ---------------- bf16 MFMA GEMM: C[M,N] (+)= A[M,K] @ Wt[N,K]^T + epi ----------------
// 128x128 tile, BK=64, 4 waves (2x2), each wave 64x64 (4x4 frags of 16x16x32).
// LDS linear [row][64] bf16 (128B rows); XOR granule swizzle applied on the
// GLOBAL source (stage) and on the ds_read byte offset (both-sides, rule #21).
enum { EPI_NONE = 0, EPI_BIAS_RELU = 1, EPI_BIAS_GELU = 2, EPI_BIAS_RES = 3 };

template <int EPI, int OBF16>
__global__ __launch_bounds__(256)
void k_gemm_bf(const ushort_t* __restrict__ A, const ushort_t* __restrict__ Wt,
               const float* __restrict__ bias, void* __restrict__ Cv,
               int M, int K, int N, long sAb, long sCb)
{
    __shared__ ushort_t As[128 * 64];
    __shared__ ushort_t Bs[128 * 64];
    const int t    = threadIdx.x;
    const int lane = t & 63;
    const int w    = t >> 6;
    const int l15  = lane & 15;
    const int lhi  = lane >> 4;
    const int wr   = w >> 1, wc = w & 1;
    const long bm = (long)blockIdx.y * 128, bn = (long)blockIdx.x * 128;
    A += (long)blockIdx.z * sAb;
    float*    Cf = (float*)Cv    + (long)blockIdx.z * sCb;
    ushort_t* Cb = (ushort_t*)Cv + (long)blockIdx.z * sCb;

    // staging geometry: chunk c = i*256 + t ; row = c>>3, granule s = c&7
    // global col = (s ^ (row&7))*8  (inverse swizzle on source)
    int srow[4], scol[4];
    #pragma unroll
    for (int i = 0; i < 4; ++i) {
        const int c = i * 256 + t;
        srow[i] = c >> 3;
        scol[i] = ((c & 7) ^ (srow[i] & 7)) << 3;
    }

    f32x4 acc[4][4] = {};

    for (int k0 = 0; k0 < K; k0 += 64) {
        __syncthreads();   // prev tile fully consumed
        #pragma unroll
        for (int i = 0; i < 4; ++i) {
            long ar = bm + srow[i]; if (ar >= M) ar = M - 1;
            gload_lds16(A + ar * (long)K + k0 + scol[i],
                        &As[(i * 256 + (t & ~63)) * 8]);
        }
        #pragma unroll
        for (int i = 0; i < 4; ++i) {
            gload_lds16(Wt + (bn + srow[i]) * (long)K + k0 + scol[i],
                        &Bs[(i * 256 + (t & ~63)) * 8]);
        }
        asm volatile("s_waitcnt vmcnt(0)" ::: "memory");
        __syncthreads();

        #pragma unroll
        for (int ks = 0; ks < 2; ++ks) {
            bf16x8 af[4], bfr[4];
            #pragma unroll
            for (int m = 0; m < 4; ++m) {
                const int row = wr * 64 + m * 16 + l15;
                const int cb  = (ks * 64 + lhi * 16) ^ ((row & 7) << 4);
                af[m] = *(const bf16x8*)((const char*)As + row * 128 + cb);
            }
            #pragma unroll
            for (int n = 0; n < 4; ++n) {
                const int row = wc * 64 + n * 16 + l15;
                const int cb  = (ks * 64 + lhi * 16) ^ ((row & 7) << 4);
                bfr[n] = *(const bf16x8*)((const char*)Bs + row * 128 + cb);
            }
            #pragma unroll
            for (int m = 0; m < 4; ++m)
                #pragma unroll
                for (int n = 0; n < 4; ++n)
                    acc[m][n] = __builtin_amdgcn_mfma_f32_16x16x32_bf16(af[m], bfr[n], acc[m][n], 0, 0, 0);
        }
    }

    // epilogue: C row = lhi*4 + j, col = l15 within each 16x16 frag
    #pragma unroll
    for (int m = 0; m < 4; ++m) {
        #pragma unroll
        for (int j = 0; j < 4; ++j) {
            const long mg = bm + wr * 64 + m * 16 + lhi * 4 + j;
            if (mg < M) {
                #pragma unroll
                for (int n = 0; n < 4; ++n) {
                    const long ng = bn + wc * 64 + n * 16 + l15;
                    float r = acc[m][n][j];
                    if (EPI != EPI_NONE) r += bias[ng];
                    if (EPI == EPI_BIAS_RELU) r = fmaxf(r, 0.f);
                    if (EPI == EPI_BIAS_GELU) r = 0.5f * r * (1.f + erff(r * 0.70710678118654752f));
                    if (OBF16) Cb[mg * N + ng] = f2bf(r);
                    else if (EPI == EPI_BIAS_RES) Cf[mg * N + ng] += r;
                    else Cf[mg * N + ng] = r;
                }
            }
        }
    }
}

// ---------------- LayerNorm over rows of 512, bf16 out ----------------
__global__ __launch_bounds__(256)
void k_ln(const float* __restrict__ x, ushort_t* __restrict__ y,
          const float* __restrict__ g, const float* __restrict__ b)
{
    __shared__ float sh[4];
    const long row = blockIdx.x;
    const float* xr = x + row * DMODEL;
    const int t = threadIdx.x;
    const float v0 = xr[t], v1 = xr[t + 256];
    const float s  = block_reduce_sum_256(v0 + v1, sh);
    const float s2 = block_reduce_sum_256(v0 * v0 + v1 * v1, sh);
    const float mu = s * (1.f / DMODEL);
    const float var = s2 * (1.f / DMODEL) - mu * mu;
    const float rs = rsqrtf(var + 1e-5f);
    y[row * DMODEL + t]       = f2bf((v0 - mu) * rs * g[t] + b[t]);
    y[row * DMODEL + t + 256] = f2bf((v1 - mu) * rs * g[t + 256] + b[t + 256]);
}

// ---------------- build bf16 K rows: [b][klen][512] ----------------
__global__ __launch_bounds__(256)
void k_build_k(const ushort_t* __restrict__ qkvb, const float* __restrict__ mems,
               const float* __restrict__ pos, ushort_t* __restrict__ kf, int layer)
{
    const int jb = blockIdx.x * 64;
    const int b  = blockIdx.y;
    const int t  = threadIdx.x;
    for (int r = 0; r < 64; ++r) {
        const int j = jb + r;
        if (j >= KLEN) break;
        #pragma unroll
        for (int half = 0; half < 2; ++half) {
            const int d = t + half * 256;
            float val;
            if (j < NTOK) val = bf2f(qkvb[((long)b * NTOK + j) * 1536 + 512 + d]);
            else          val = mems[(((long)layer * B_SZ + b) * MEMLEN + (j - NTOK)) * DMODEL + d];
            val += pos[(long)j * DMODEL + d];
            kf[((long)b * KLEN + j) * DMODEL + d] = f2bf(val);
        }
    }
}

// ---------------- build bf16 V transposed: [b*8+h][d=64][KLEN_PAD] ----------------
__global__ __launch_bounds__(256)
void k_build_vt(const ushort_t* __restrict__ qkvb, const float* __restrict__ mems,
                const float* __restrict__ pos, ushort_t* __restrict__ vt, int layer)
{
    __shared__ ushort_t tile[64][65];
    const int jb = blockIdx.x * 64;
    const int b  = blockIdx.y;
    const int h  = blockIdx.z;
    const int t  = threadIdx.x;
    #pragma unroll
    for (int rep = 0; rep < 16; ++rep) {
        const int idx = rep * 256 + t;
        const int r = idx >> 6, c = idx & 63;
        const int j = jb + r;
        float val = 0.f;
        if (j < NTOK)
            val = bf2f(qkvb[((long)b * NTOK + j) * 1536 + 1024 + h * 64 + c]) + pos[(long)j * DMODEL + h * 64 + c];
        else if (j < KLEN)
            val = mems[(((long)layer * B_SZ + b) * MEMLEN + (j - NTOK)) * DMODEL + h * 64 + c]
                + pos[(long)j * DMODEL + h * 64 + c];
        tile[c][r] = f2bf(val);
    }
    __syncthreads();
    #pragma unroll
    for (int rep = 0; rep < 16; ++rep) {
        const int idx = rep * 256 + t;
        const int d = idx >> 6, r = idx & 63;
        vt[(((long)b * NHEAD + h) * 64 + d) * (long)KLEN_PAD + jb + r] = tile[d][r];
    }
}

// ---------------- MFMA flash attention: 64-query tile, 4 waves ----------------
#define LDSP 72

__global__ __launch_bounds__(256)
void k_attn_mfma(const ushort_t* __restrict__ qkvb,
                 const ushort_t* __restrict__ kf,
                 const ushort_t* __restrict__ vt,
                 ushort_t* __restrict__ outp)
{
    __shared__ ushort_t QPs[64][LDSP];
    __shared__ ushort_t Ks [64][LDSP];
    __shared__ ushort_t Vts[64][LDSP];

    const int t    = threadIdx.x;
    const int lane = t & 63;
    const int w    = t >> 6;
    const int l15  = lane & 15;
    const int lhi  = lane >> 4;
    const int qb   = blockIdx.x * 64;
    const int h    = blockIdx.y;
    const int b    = blockIdx.z;

    // ---- stage Q (bf16 direct copy) ----
    {
        const int r  = t >> 2;
        const int c0 = (t & 3) * 16;
        const int qg = qb + r;
        uint4 u0 = make_uint4(0,0,0,0), u1 = make_uint4(0,0,0,0);
        if (qg < NTOK) {
            const ushort_t* src = qkvb + ((long)b * NTOK + qg) * 1536 + h * 64 + c0;
            u0 = ((const uint4*)src)[0];
            u1 = ((const uint4*)src)[1];
        }
        *(uint4*)&QPs[r][c0]     = u0;
        *(uint4*)&QPs[r][c0 + 8] = u1;
    }
    __syncthreads();
    bf16x8 q_frag[2];
    #pragma unroll
    for (int ks = 0; ks < 2; ++ks)
        q_frag[ks] = *(const bf16x8*)&QPs[w * 16 + l15][ks * 32 + lhi * 8];

    f32x4 o_frag[4] = {};
    float m_run[4] = {NEG_BIG, NEG_BIG, NEG_BIG, NEG_BIG};
    float l_run[4] = {0.f, 0.f, 0.f, 0.f};

    const ushort_t* kbase = kf + (long)b * KLEN * DMODEL + h * 64;
    const ushort_t* vbase = vt + ((long)b * NHEAD + h) * 64 * (long)KLEN_PAD;

    for (int kt = 0; kt < 65; ++kt) {
        const int kb = kt * 64;
        __syncthreads();
        {
            const int r = t >> 2;
            const int jg = kb + r;
            #pragma unroll
            for (int cc = 0; cc < 2; ++cc) {
                const int c8 = (t & 3) * 2 + cc;
                uint4 kv = make_uint4(0u, 0u, 0u, 0u);
                if (jg < KLEN) kv = *(const uint4*)(kbase + (long)jg * DMODEL + c8 * 8);
                *(uint4*)&Ks[r][c8 * 8] = kv;
                const uint4 vv = *(const uint4*)(vbase + (long)r * KLEN_PAD + kb + c8 * 8);
                *(uint4*)&Vts[r][c8 * 8] = vv;
            }
        }
        __syncthreads();

        f32x4 s_frag[4];
        #pragma unroll
        for (int n = 0; n < 4; ++n) {
            f32x4 acc = {0.f, 0.f, 0.f, 0.f};
            #pragma unroll
            for (int ks = 0; ks < 2; ++ks) {
                const bf16x8 kfr = *(const bf16x8*)&Ks[n * 16 + l15][ks * 32 + lhi * 8];
                acc = __builtin_amdgcn_mfma_f32_16x16x32_bf16(q_frag[ks], kfr, acc, 0, 0, 0);
            }
            s_frag[n] = acc;
        }

        #pragma unroll
        for (int i = 0; i < 4; ++i) {
            float sv[4];
            #pragma unroll
            for (int n = 0; n < 4; ++n) {
                const int cg = kb + n * 16 + l15;
                sv[n] = (cg < KLEN) ? s_frag[n][i] * ATT_SCALE : NEG_BIG;
            }
            float mx = fmaxf(fmaxf(sv[0], sv[1]), fmaxf(sv[2], sv[3]));
            mx = fmaxf(mx, __shfl_xor(mx, 1));
            mx = fmaxf(mx, __shfl_xor(mx, 2));
            mx = fmaxf(mx, __shfl_xor(mx, 4));
            mx = fmaxf(mx, __shfl_xor(mx, 8));
            const float mnew  = fmaxf(m_run[i], mx);
            const float alpha = __expf(m_run[i] - mnew);
            float lsum = 0.f;
            ushort_t pb[4];
            #pragma unroll
            for (int n = 0; n < 4; ++n) {
                const float p = __expf(sv[n] - mnew);
                lsum += p;
                pb[n] = f2bf(p);
            }
            lsum += __shfl_xor(lsum, 1);
            lsum += __shfl_xor(lsum, 2);
            lsum += __shfl_xor(lsum, 4);
            lsum += __shfl_xor(lsum, 8);
            l_run[i] = l_run[i] * alpha + lsum;
            m_run[i] = mnew;
            #pragma unroll
            for (int n = 0; n < 4; ++n) {
                o_frag[n][i] *= alpha;
                QPs[w * 16 + lhi * 4 + i][n * 16 + l15] = pb[n];
            }
        }
        __syncthreads();

        #pragma unroll
        for (int n = 0; n < 4; ++n) {
            #pragma unroll
            for (int ks = 0; ks < 2; ++ks) {
                const bf16x8 pa = *(const bf16x8*)&QPs[w * 16 + l15][ks * 32 + lhi * 8];
                const bf16x8 vb = *(const bf16x8*)&Vts[n * 16 + l15][ks * 32 + lhi * 8];
                o_frag[n] = __builtin_amdgcn_mfma_f32_16x16x32_bf16(pa, vb, o_frag[n], 0, 0, 0);
            }
        }
    }

    #pragma unroll
    for (int i = 0; i < 4; ++i) {
        const int rg = qb + w * 16 + lhi * 4 + i;
        if (rg < NTOK) {
            const float inv = 1.f / l_run[i];
            ushort_t* op = outp + ((long)b * NTOK + rg) * DMODEL + h * 64 + l15;
            #pragma unroll
            for (int n = 0; n < 4; ++n) op[n * 16] = f2bf(o_frag[n][i] * inv);
        }
    }
}

// ---------------- final LN + 2-class head on cls row ----------------
__global__ __launch_bounds__(256)
void k_final(const float* __restrict__ x, const float* __restrict__ g,
             const float* __restrict__ bb, const float* __restrict__ w2,
             const float* __restrict__ b2, float* __restrict__ out)
{
    __shared__ float sh[4];
    const int b = blockIdx.x;
    const float* xr = x + (long)b * NTOK * DMODEL;
    const int t = threadIdx.x;
    const float v0 = xr[t], v1 = xr[t + 256];
    const float s  = block_reduce_sum_256(v0 + v1, sh);
    const float s2 = block_reduce_sum_256(v0 * v0 + v1 * v1, sh);
    const float mu = s * (1.f / DMODEL);
    const float var = s2 * (1.f / DMODEL) - mu * mu;
    const float rs = rsqrtf(var + 1e-5f);
    const float n0 = (v0 - mu) * rs * g[t] + bb[t];
    const float n1 = (v1 - mu) * rs * g[t + 256] + bb[t + 256];
    const float p0 = block_reduce_sum_256(n0 * w2[t * 2 + 0] + n1 * w2[(t + 256) * 2 + 0], sh);
    const float p1 = block_reduce_sum_256(n0 * w2[t * 2 + 1] + n1 * w2[(t + 256) * 2 + 1], sh);
    if (t == 0) {
        out[b * 2 + 0] = p0 + b2[0];
        out[b * 2 + 1] = p1 + b2[1];
    }
}

// ---------------- host orchestration ----------------
extern "C" void kernel_launch(void* const* d_in, const int* in_sizes, int n_in,
                              void* d_out, int out_size, void* d_ws, size_t ws_size,
                              hipStream_t stream)
{
    const float* data    = (const float*)d_in[0];
    const float* mems    = (const float*)d_in[1];
    const float* fc1_w   = (const float*)d_in[2];
    const float* fc1_b   = (const float*)d_in[3];
    const float* cls     = (const float*)d_in[4];
    const float* ln1_g   = (const float*)d_in[5];
    const float* ln1_b   = (const float*)d_in[6];
    const float* qkv_w   = (const float*)d_in[7];
    const float* out_w   = (const float*)d_in[8];
    const float* out_b   = (const float*)d_in[9];
    const float* ln2_g   = (const float*)d_in[10];
    const float* ln2_b   = (const float*)d_in[11];
    const float* ff_w1   = (const float*)d_in[12];
    const float* ff_b1   = (const float*)d_in[13];
    const float* ff_w2   = (const float*)d_in[14];
    const float* ff_b2   = (const float*)d_in[15];
    const float* normf_g = (const float*)d_in[16];
    const float* normf_b = (const float*)d_in[17];
    const float* fc2_w   = (const float*)d_in[18];
    const float* fc2_b   = (const float*)d_in[19];
    float* out = (float*)d_out;

    const int MROWS = B_SZ * NTOK;                          // 8194
    const int MT128 = (MROWS + 127) / 128;                  // 65

    // ---- workspace layout ----
    char* p = (char*)d_ws;
    float* x   = (float*)p;            p += (long)B_SZ * NTOK * DMODEL * 4;   // 16.8 MB
    float* pos = (float*)p;            p += (long)KLEN * DMODEL * 4;          //  8.4 MB
    ushort_t* data_bf = (ushort_t*)p;  p += (long)B_SZ * 4096 * INDIM * 2;    // 16.8 MB
    ushort_t* actA    = (ushort_t*)p;  p += (long)MROWS * DMODEL * 2;         //  8.4 MB
    ushort_t* actB    = (ushort_t*)p;  p += (long)MROWS * DMODEL * 2;         //  8.4 MB
    ushort_t* fc1_wt  = (ushort_t*)p;  p += (long)DMODEL * INDIM * 2;
    ushort_t* qkv_wt  = (ushort_t*)p;  p += (long)2 * 1536 * DMODEL * 2;
    ushort_t* out_wt  = (ushort_t*)p;  p += (long)2 * DMODEL * DMODEL * 2;
    ushort_t* ff1_wt  = (ushort_t*)p;  p += (long)2 * MLPD * DMODEL * 2;
    ushort_t* ff2_wt  = (ushort_t*)p;  p += (long)2 * DMODEL * MLPD * 2;
    // scratch union: {qkv_bf + kf + vt} vs {ffbuf}
    ushort_t* qkv_bf  = (ushort_t*)p;                                          // [8194][1536]
    ushort_t* kf      = qkv_bf + (long)MROWS * 1536;                           // [2][4105][512]
    ushort_t* vt      = kf + (long)B_SZ * KLEN * DMODEL;                       // [16][64][4160]
    ushort_t* ffbuf   = qkv_bf;                                                // [8194][2048]

    // ---- one-time converts (per launch; cheap, memory-bound) ----
    k_f2b<<<dim3(2048), dim3(256), 0, stream>>>(data, data_bf, (long)B_SZ * 4096 * INDIM / 4);
    k_w2bt<<<dim3(DMODEL/64, INDIM/64, 1),  dim3(256), 0, stream>>>(fc1_w, fc1_wt, INDIM, DMODEL);
    k_w2bt<<<dim3(1536/64, DMODEL/64, 2),   dim3(256), 0, stream>>>(qkv_w, qkv_wt, DMODEL, 1536);
    k_w2bt<<<dim3(DMODEL/64, DMODEL/64, 2), dim3(256), 0, stream>>>(out_w, out_wt, DMODEL, DMODEL);
    k_w2bt<<<dim3(MLPD/64, DMODEL/64, 2),   dim3(256), 0, stream>>>(ff_w1, ff1_wt, DMODEL, MLPD);
    k_w2bt<<<dim3(DMODEL/64, MLPD/64, 2),   dim3(256), 0, stream>>>(ff_w2, ff2_wt, MLPD, DMODEL);

    k_pos<<<dim3(KLEN), dim3(256), 0, stream>>>(pos);
    k_cls<<<dim3(B_SZ), dim3(512), 0, stream>>>(cls, x);

    // fc1 + ReLU -> x rows 1..4096 per batch (fp32 out)
    k_gemm_bf<EPI_BIAS_RELU, 0><<<dim3(DMODEL/128, 4096/128, B_SZ), dim3(256), 0, stream>>>(
        data_bf, fc1_wt, fc1_b, x + DMODEL, 4096, INDIM, DMODEL,
        (long)4096 * INDIM, (long)NTOK * DMODEL);

    for (int l = 0; l < 2; ++l) {
        k_ln<<<dim3(MROWS), dim3(256), 0, stream>>>(x, actA, ln1_g + l * DMODEL, ln1_b + l * DMODEL);
        k_gemm_bf<EPI_NONE, 1><<<dim3(1536/128, MT128, 1), dim3(256), 0, stream>>>(
            actA, qkv_wt + (long)l * 1536 * DMODEL, nullptr, qkv_bf, MROWS, DMODEL, 1536, 0, 0);
        k_build_k <<<dim3((KLEN + 63)/64, B_SZ), dim3(256), 0, stream>>>(qkv_bf, mems, pos, kf, l);
        k_build_vt<<<dim3(KLEN_PAD/64, B_SZ, NHEAD), dim3(256), 0, stream>>>(qkv_bf, mems, pos, vt, l);
        k_attn_mfma<<<dim3((NTOK + 63)/64, NHEAD, B_SZ), dim3(256), 0, stream>>>(qkv_bf, kf, vt, actB);
        k_gemm_bf<EPI_BIAS_RES, 0><<<dim3(DMODEL/128, MT128, 1), dim3(256), 0, stream>>>(
            actB, out_wt + (long)l * DMODEL * DMODEL, out_b + l * DMODEL, x, MROWS, DMODEL, DMODEL, 0, 0);
        k_ln<<<dim3(MROWS), dim3(256), 0, stream>>>(x, actA, ln2_g + l * DMODEL, ln2_b + l * DMODEL);
        k_gemm_bf<EPI_BIAS_GELU, 1><<<dim3(MLPD/128, MT128, 1), dim3(256), 0, stream>>>(
            actA, ff1_wt + (long)l * MLPD * DMODEL, ff_b1 + l * MLPD, ffbuf, MROWS, DMODEL, MLPD, 0, 0);
        k_gemm_bf<EPI_BIAS_RES, 0><<<dim3(DMODEL/128, MT128, 1), dim3(256), 0, stream>>>(
            ffbuf, ff2_wt + (long)l * DMODEL * MLPD, ff_b2 + l * DMODEL, x, MROWS, MLPD, DMODEL, 0, 0);
    }

    k_final<<<dim3(B_SZ), dim3(256), 0, stream>>>(x, normf_g, normf_b, fc2_w, fc2_b, out);
}

// Round 5
// 1193.269 us; speedup vs baseline: 4.0667x; 1.0653x over previous
//
#include <hip/hip_runtime.h>
#include <hip/hip_bf16.h>
#include <math.h>

// ---------------- problem constants ----------------
#define B_SZ   2
#define NTOK   4097      // n = 4096 + cls
#define KLEN   4105      // n + mem_len(8)
#define KLEN_PAD 4160    // 65 * 64
#define DMODEL 512
#define INDIM  1024
#define NHEAD  8
#define DHEAD  64
#define MLPD   2048
#define MEMLEN 8
#define ATT_SCALE 0.125f // 1/sqrt(64)
#define NEG_BIG  -1.0e30f

typedef unsigned short ushort_t;
typedef short bf16x8 __attribute__((ext_vector_type(8)));
typedef float f32x4  __attribute__((ext_vector_type(4)));

__device__ __forceinline__ unsigned short f2bf(float f) {
    union { float f; unsigned u; } v; v.f = f;
    const unsigned r = v.u + 0x7fff + ((v.u >> 16) & 1);   // RTNE
    return (unsigned short)(r >> 16);
}
__device__ __forceinline__ float bf2f(unsigned short u) {
    union { unsigned u; float f; } v; v.u = ((unsigned)u) << 16;
    return v.f;
}

// async global->LDS, 16B per lane; lds base must be wave-uniform
__device__ __forceinline__ void gload_lds16(const void* g, void* l) {
    __builtin_amdgcn_global_load_lds(
        (const __attribute__((address_space(1))) unsigned int*)g,
        (__attribute__((address_space(3))) unsigned int*)l, 16, 0, 0);
}

// ---------------- small helpers ----------------
__device__ __forceinline__ float block_reduce_sum_256(float v, float* sh) {
    #pragma unroll
    for (int m = 1; m < 64; m <<= 1) v += __shfl_xor(v, m);
    const int w = threadIdx.x >> 6;
    if ((threadIdx.x & 63) == 0) sh[w] = v;
    __syncthreads();
    float r = sh[0] + sh[1] + sh[2] + sh[3];
    __syncthreads();
    return r;
}

// ---------------- pos emb ----------------
__global__ void k_pos(float* __restrict__ pos) {
    const int p = blockIdx.x;
    const int j = threadIdx.x;
    const float position = (float)(KLEN - 1 - p);
    const float inv_freq = 1.0f / powf(10000.0f, (float)j / 256.0f);
    const float x = position * inv_freq;
    pos[(long)p * DMODEL + j]       = sinf(x);
    pos[(long)p * DMODEL + 256 + j] = cosf(x);
}

// ---------------- cls token ----------------
__global__ void k_cls(const float* __restrict__ cls, float* __restrict__ x) {
    const int b = blockIdx.x;
    x[(long)b * NTOK * DMODEL + threadIdx.x] = cls[threadIdx.x];
}

// ---------------- fp32 -> bf16 convert (grid-stride, float4) ----------------
__global__ __launch_bounds__(256)
void k_f2b(const float* __restrict__ in, ushort_t* __restrict__ out, long n4) {
    for (long i = blockIdx.x * 256 + threadIdx.x; i < n4; i += (long)gridDim.x * 256) {
        const float4 f = ((const float4*)in)[i];
        ushort4 u;
        u.x = f2bf(f.x); u.y = f2bf(f.y); u.z = f2bf(f.z); u.w = f2bf(f.w);
        ((ushort4*)out)[i] = u;
    }
}

// ---------------- weight fp32[K][N] -> bf16 Wt[N][K] (tiled transpose) ----------------
__global__ __launch_bounds__(256)
void k_w2bt(const float* __restrict__ W, ushort_t* __restrict__ Wt, int K, int N) {
    __shared__ float tile[64][65];
    W  += (long)blockIdx.z * K * N;
    Wt += (long)blockIdx.z * N * K;
    const int n0 = blockIdx.x * 64, k0 = blockIdx.y * 64;
    const int t = threadIdx.x;
    #pragma unroll
    for (int rep = 0; rep < 16; ++rep) {
        const int idx = rep * 256 + t;
        const int r = idx >> 6, c = idx & 63;
        tile[r][c] = W[(long)(k0 + r) * N + n0 + c];
    }
    __syncthreads();
    #pragma unroll
    for (int rep = 0; rep < 16; ++rep) {
        const int idx = rep * 256 + t;
        const int n = idx >> 6, kk = idx & 63;
        Wt[(long)(n0 + n) * K + k0 + kk] = f2bf(tile[kk][n]);
    }
}

// ---------------- bf16 MFMA GEMM: C[M,N] (+)= A[M,K] @ Wt[N,K]^T + epi ----------------
enum { EPI_NONE = 0, EPI_BIAS_RELU = 1, EPI_BIAS_GELU = 2, EPI_BIAS_RES = 3 };

template <int EPI, int OBF16>
__global__ __launch_bounds__(256)
void k_gemm_bf(const ushort_t* __restrict__ A, const ushort_t* __restrict__ Wt,
               const float* __restrict__ bias, void* __restrict__ Cv,
               int M, int K, int N, long sAb, long sCb)
{
    __shared__ ushort_t As[128 * 64];
    __shared__ ushort_t Bs[128 * 64];
    const int t    = threadIdx.x;
    const int lane = t & 63;
    const int w    = t >> 6;
    const int l15  = lane & 15;
    const int lhi  = lane >> 4;
    const int wr   = w >> 1, wc = w & 1;
    const long bm = (long)blockIdx.y * 128, bn = (long)blockIdx.x * 128;
    A += (long)blockIdx.z * sAb;
    float*    Cf = (float*)Cv    + (long)blockIdx.z * sCb;
    ushort_t* Cb = (ushort_t*)Cv + (long)blockIdx.z * sCb;

    int srow[4], scol[4];
    #pragma unroll
    for (int i = 0; i < 4; ++i) {
        const int c = i * 256 + t;
        srow[i] = c >> 3;
        scol[i] = ((c & 7) ^ (srow[i] & 7)) << 3;
    }

    f32x4 acc[4][4] = {};

    for (int k0 = 0; k0 < K; k0 += 64) {
        __syncthreads();
        #pragma unroll
        for (int i = 0; i < 4; ++i) {
            long ar = bm + srow[i]; if (ar >= M) ar = M - 1;
            gload_lds16(A + ar * (long)K + k0 + scol[i],
                        &As[(i * 256 + (t & ~63)) * 8]);
        }
        #pragma unroll
        for (int i = 0; i < 4; ++i) {
            gload_lds16(Wt + (bn + srow[i]) * (long)K + k0 + scol[i],
                        &Bs[(i * 256 + (t & ~63)) * 8]);
        }
        asm volatile("s_waitcnt vmcnt(0)" ::: "memory");
        __syncthreads();

        #pragma unroll
        for (int ks = 0; ks < 2; ++ks) {
            bf16x8 af[4], bfr[4];
            #pragma unroll
            for (int m = 0; m < 4; ++m) {
                const int row = wr * 64 + m * 16 + l15;
                const int cb  = (ks * 64 + lhi * 16) ^ ((row & 7) << 4);
                af[m] = *(const bf16x8*)((const char*)As + row * 128 + cb);
            }
            #pragma unroll
            for (int n = 0; n < 4; ++n) {
                const int row = wc * 64 + n * 16 + l15;
                const int cb  = (ks * 64 + lhi * 16) ^ ((row & 7) << 4);
                bfr[n] = *(const bf16x8*)((const char*)Bs + row * 128 + cb);
            }
            #pragma unroll
            for (int m = 0; m < 4; ++m)
                #pragma unroll
                for (int n = 0; n < 4; ++n)
                    acc[m][n] = __builtin_amdgcn_mfma_f32_16x16x32_bf16(af[m], bfr[n], acc[m][n], 0, 0, 0);
        }
    }

    #pragma unroll
    for (int m = 0; m < 4; ++m) {
        #pragma unroll
        for (int j = 0; j < 4; ++j) {
            const long mg = bm + wr * 64 + m * 16 + lhi * 4 + j;
            if (mg < M) {
                #pragma unroll
                for (int n = 0; n < 4; ++n) {
                    const long ng = bn + wc * 64 + n * 16 + l15;
                    float r = acc[m][n][j];
                    if (EPI != EPI_NONE) r += bias[ng];
                    if (EPI == EPI_BIAS_RELU) r = fmaxf(r, 0.f);
                    if (EPI == EPI_BIAS_GELU) r = 0.5f * r * (1.f + erff(r * 0.70710678118654752f));
                    if (OBF16) Cb[mg * N + ng] = f2bf(r);
                    else if (EPI == EPI_BIAS_RES) Cf[mg * N + ng] += r;
                    else Cf[mg * N + ng] = r;
                }
            }
        }
    }
}

// ---------------- LayerNorm over rows of 512, bf16 out; rstride picks rows ----------------
__global__ __launch_bounds__(256)
void k_ln(const float* __restrict__ x, ushort_t* __restrict__ y,
          const float* __restrict__ g, const float* __restrict__ b, long rstride)
{
    __shared__ float sh[4];
    const long row = (long)blockIdx.x * rstride;
    const float* xr = x + row * DMODEL;
    const int t = threadIdx.x;
    const float v0 = xr[t], v1 = xr[t + 256];
    const float s  = block_reduce_sum_256(v0 + v1, sh);
    const float s2 = block_reduce_sum_256(v0 * v0 + v1 * v1, sh);
    const float mu = s * (1.f / DMODEL);
    const float var = s2 * (1.f / DMODEL) - mu * mu;
    const float rs = rsqrtf(var + 1e-5f);
    y[row * DMODEL + t]       = f2bf((v0 - mu) * rs * g[t] + b[t]);
    y[row * DMODEL + t + 256] = f2bf((v1 - mu) * rs * g[t + 256] + b[t + 256]);
}

// ---------------- build bf16 K rows: [b][klen][512] ----------------
__global__ __launch_bounds__(256)
void k_build_k(const ushort_t* __restrict__ qkvb, const float* __restrict__ mems,
               const float* __restrict__ pos, ushort_t* __restrict__ kf, int layer)
{
    const int jb = blockIdx.x * 64;
    const int b  = blockIdx.y;
    const int t  = threadIdx.x;
    for (int r = 0; r < 64; ++r) {
        const int j = jb + r;
        if (j >= KLEN) break;
        #pragma unroll
        for (int half = 0; half < 2; ++half) {
            const int d = t + half * 256;
            float val;
            if (j < NTOK) val = bf2f(qkvb[((long)b * NTOK + j) * 1536 + 512 + d]);
            else          val = mems[(((long)layer * B_SZ + b) * MEMLEN + (j - NTOK)) * DMODEL + d];
            val += pos[(long)j * DMODEL + d];
            kf[((long)b * KLEN + j) * DMODEL + d] = f2bf(val);
        }
    }
}

// ---------------- build bf16 V transposed: [b*8+h][d=64][KLEN_PAD] ----------------
__global__ __launch_bounds__(256)
void k_build_vt(const ushort_t* __restrict__ qkvb, const float* __restrict__ mems,
                const float* __restrict__ pos, ushort_t* __restrict__ vt, int layer)
{
    __shared__ ushort_t tile[64][65];
    const int jb = blockIdx.x * 64;
    const int b  = blockIdx.y;
    const int h  = blockIdx.z;
    const int t  = threadIdx.x;
    #pragma unroll
    for (int rep = 0; rep < 16; ++rep) {
        const int idx = rep * 256 + t;
        const int r = idx >> 6, c = idx & 63;
        const int j = jb + r;
        float val = 0.f;
        if (j < NTOK)
            val = bf2f(qkvb[((long)b * NTOK + j) * 1536 + 1024 + h * 64 + c]) + pos[(long)j * DMODEL + h * 64 + c];
        else if (j < KLEN)
            val = mems[(((long)layer * B_SZ + b) * MEMLEN + (j - NTOK)) * DMODEL + h * 64 + c]
                + pos[(long)j * DMODEL + h * 64 + c];
        tile[c][r] = f2bf(val);
    }
    __syncthreads();
    #pragma unroll
    for (int rep = 0; rep < 16; ++rep) {
        const int idx = rep * 256 + t;
        const int d = idx >> 6, r = idx & 63;
        vt[(((long)b * NHEAD + h) * 64 + d) * (long)KLEN_PAD + jb + r] = tile[d][r];
    }
}

// ---------------- MFMA flash attention: 128-query tile, 4 waves ----------------
// Each wave owns rows {m*64 + w*16 .. +15} for m in {0,1}; K/V frags shared across m.
#define LDSP 72

__global__ __launch_bounds__(256)
void k_attn_mfma(const ushort_t* __restrict__ qkvb,
                 const ushort_t* __restrict__ kf,
                 const ushort_t* __restrict__ vt,
                 ushort_t* __restrict__ outp)
{
    __shared__ ushort_t QPs[128][LDSP];  // Q at start, then reused as P
    __shared__ ushort_t Ks [64][LDSP];
    __shared__ ushort_t Vts[64][LDSP];

    const int t    = threadIdx.x;
    const int lane = t & 63;
    const int w    = t >> 6;
    const int l15  = lane & 15;
    const int lhi  = lane >> 4;
    const int qb   = blockIdx.x * 128;
    const int h    = blockIdx.y;
    const int b    = blockIdx.z;

    // ---- stage Q (bf16 direct copy): 128 rows x 64 ----
    #pragma unroll
    for (int rep = 0; rep < 2; ++rep) {
        const int idx = rep * 256 + t;   // 0..511
        const int r   = idx >> 2;        // 0..127
        const int c0  = (idx & 3) * 16;  // 0,16,32,48
        const int qg  = qb + r;
        uint4 u0 = make_uint4(0,0,0,0), u1 = make_uint4(0,0,0,0);
        if (qg < NTOK) {
            const ushort_t* src = qkvb + ((long)b * NTOK + qg) * 1536 + h * 64 + c0;
            u0 = ((const uint4*)src)[0];
            u1 = ((const uint4*)src)[1];
        }
        *(uint4*)&QPs[r][c0]     = u0;
        *(uint4*)&QPs[r][c0 + 8] = u1;
    }
    __syncthreads();
    bf16x8 q_frag[2][2];
    #pragma unroll
    for (int m = 0; m < 2; ++m)
        #pragma unroll
        for (int ks = 0; ks < 2; ++ks)
            q_frag[m][ks] = *(const bf16x8*)&QPs[m * 64 + w * 16 + l15][ks * 32 + lhi * 8];

    f32x4 o_frag[2][4] = {};
    float m_run[2][4], l_run[2][4];
    #pragma unroll
    for (int m = 0; m < 2; ++m)
        #pragma unroll
        for (int i = 0; i < 4; ++i) { m_run[m][i] = NEG_BIG; l_run[m][i] = 0.f; }

    const ushort_t* kbase = kf + (long)b * KLEN * DMODEL + h * 64;
    const ushort_t* vbase = vt + ((long)b * NHEAD + h) * 64 * (long)KLEN_PAD;

    for (int kt = 0; kt < 65; ++kt) {
        const int kb = kt * 64;
        __syncthreads();
        {
            const int r = t >> 2;
            const int jg = kb + r;
            #pragma unroll
            for (int cc = 0; cc < 2; ++cc) {
                const int c8 = (t & 3) * 2 + cc;
                uint4 kv = make_uint4(0u, 0u, 0u, 0u);
                if (jg < KLEN) kv = *(const uint4*)(kbase + (long)jg * DMODEL + c8 * 8);
                *(uint4*)&Ks[r][c8 * 8] = kv;
                const uint4 vv = *(const uint4*)(vbase + (long)r * KLEN_PAD + kb + c8 * 8);
                *(uint4*)&Vts[r][c8 * 8] = vv;
            }
        }
        __syncthreads();

        // ---- S = Q @ K^T ; K-fragments reused across both m-blocks ----
        bf16x8 kfr[4][2];
        #pragma unroll
        for (int n = 0; n < 4; ++n)
            #pragma unroll
            for (int ks = 0; ks < 2; ++ks)
                kfr[n][ks] = *(const bf16x8*)&Ks[n * 16 + l15][ks * 32 + lhi * 8];

        f32x4 s_frag[2][4];
        #pragma unroll
        for (int m = 0; m < 2; ++m)
            #pragma unroll
            for (int n = 0; n < 4; ++n) {
                f32x4 acc = {0.f, 0.f, 0.f, 0.f};
                #pragma unroll
                for (int ks = 0; ks < 2; ++ks)
                    acc = __builtin_amdgcn_mfma_f32_16x16x32_bf16(q_frag[m][ks], kfr[n][ks], acc, 0, 0, 0);
                s_frag[m][n] = acc;
            }

        // ---- online softmax (row = m*64 + w*16 + lhi*4 + i, col = kb + n*16 + l15) ----
        #pragma unroll
        for (int m = 0; m < 2; ++m) {
            #pragma unroll
            for (int i = 0; i < 4; ++i) {
                float sv[4];
                #pragma unroll
                for (int n = 0; n < 4; ++n) {
                    const int cg = kb + n * 16 + l15;
                    sv[n] = (cg < KLEN) ? s_frag[m][n][i] * ATT_SCALE : NEG_BIG;
                }
                float mx = fmaxf(fmaxf(sv[0], sv[1]), fmaxf(sv[2], sv[3]));
                mx = fmaxf(mx, __shfl_xor(mx, 1));
                mx = fmaxf(mx, __shfl_xor(mx, 2));
                mx = fmaxf(mx, __shfl_xor(mx, 4));
                mx = fmaxf(mx, __shfl_xor(mx, 8));
                const float mnew  = fmaxf(m_run[m][i], mx);
                const float alpha = __expf(m_run[m][i] - mnew);
                float lsum = 0.f;
                ushort_t pb[4];
                #pragma unroll
                for (int n = 0; n < 4; ++n) {
                    const float p = __expf(sv[n] - mnew);
                    lsum += p;
                    pb[n] = f2bf(p);
                }
                lsum += __shfl_xor(lsum, 1);
                lsum += __shfl_xor(lsum, 2);
                lsum += __shfl_xor(lsum, 4);
                lsum += __shfl_xor(lsum, 8);
                l_run[m][i] = l_run[m][i] * alpha + lsum;
                m_run[m][i] = mnew;
                #pragma unroll
                for (int n = 0; n < 4; ++n) {
                    o_frag[m][n][i] *= alpha;
                    QPs[m * 64 + w * 16 + lhi * 4 + i][n * 16 + l15] = pb[n];
                }
            }
        }
        __syncthreads();   // P visible

        // ---- O += P @ V ; V-fragments reused across both m-blocks ----
        bf16x8 vfr[4][2];
        #pragma unroll
        for (int n = 0; n < 4; ++n)
            #pragma unroll
            for (int ks = 0; ks < 2; ++ks)
                vfr[n][ks] = *(const bf16x8*)&Vts[n * 16 + l15][ks * 32 + lhi * 8];

        #pragma unroll
        for (int m = 0; m < 2; ++m) {
            bf16x8 pa[2];
            #pragma unroll
            for (int ks = 0; ks < 2; ++ks)
                pa[ks] = *(const bf16x8*)&QPs[m * 64 + w * 16 + l15][ks * 32 + lhi * 8];
            #pragma unroll
            for (int n = 0; n < 4; ++n)
                #pragma unroll
                for (int ks = 0; ks < 2; ++ks)
                    o_frag[m][n] = __builtin_amdgcn_mfma_f32_16x16x32_bf16(pa[ks], vfr[n][ks], o_frag[m][n], 0, 0, 0);
        }
    }

    // ---- epilogue ----
    #pragma unroll
    for (int m = 0; m < 2; ++m)
        #pragma unroll
        for (int i = 0; i < 4; ++i) {
            const int rg = qb + m * 64 + w * 16 + lhi * 4 + i;
            if (rg < NTOK) {
                const float inv = 1.f / l_run[m][i];
                ushort_t* op = outp + ((long)b * NTOK + rg) * DMODEL + h * 64 + l15;
                #pragma unroll
                for (int n = 0; n < 4; ++n) op[n * 16] = f2bf(o_frag[m][n][i] * inv);
            }
        }
}

// ---------------- final LN + 2-class head on cls row ----------------
__global__ __launch_bounds__(256)
void k_final(const float* __restrict__ x, const float* __restrict__ g,
             const float* __restrict__ bb, const float* __restrict__ w2,
             const float* __restrict__ b2, float* __restrict__ out)
{
    __shared__ float sh[4];
    const int b = blockIdx.x;
    const float* xr = x + (long)b * NTOK * DMODEL;
    const int t = threadIdx.x;
    const float v0 = xr[t], v1 = xr[t + 256];
    const float s  = block_reduce_sum_256(v0 + v1, sh);
    const float s2 = block_reduce_sum_256(v0 * v0 + v1 * v1, sh);
    const float mu = s * (1.f / DMODEL);
    const float var = s2 * (1.f / DMODEL) - mu * mu;
    const float rs = rsqrtf(var + 1e-5f);
    const float n0 = (v0 - mu) * rs * g[t] + bb[t];
    const float n1 = (v1 - mu) * rs * g[t + 256] + bb[t + 256];
    const float p0 = block_reduce_sum_256(n0 * w2[t * 2 + 0] + n1 * w2[(t + 256) * 2 + 0], sh);
    const float p1 = block_reduce_sum_256(n0 * w2[t * 2 + 1] + n1 * w2[(t + 256) * 2 + 1], sh);
    if (t == 0) {
        out[b * 2 + 0] = p0 + b2[0];
        out[b * 2 + 1] = p1 + b2[1];
    }
}

// ---------------- host orchestration ----------------
extern "C" void kernel_launch(void* const* d_in, const int* in_sizes, int n_in,
                              void* d_out, int out_size, void* d_ws, size_t ws_size,
                              hipStream_t stream)
{
    const float* data    = (const float*)d_in[0];
    const float* mems    = (const float*)d_in[1];
    const float* fc1_w   = (const float*)d_in[2];
    const float* fc1_b   = (const float*)d_in[3];
    const float* cls     = (const float*)d_in[4];
    const float* ln1_g   = (const float*)d_in[5];
    const float* ln1_b   = (const float*)d_in[6];
    const float* qkv_w   = (const float*)d_in[7];
    const float* out_w   = (const float*)d_in[8];
    const float* out_b   = (const float*)d_in[9];
    const float* ln2_g   = (const float*)d_in[10];
    const float* ln2_b   = (const float*)d_in[11];
    const float* ff_w1   = (const float*)d_in[12];
    const float* ff_b1   = (const float*)d_in[13];
    const float* ff_w2   = (const float*)d_in[14];
    const float* ff_b2   = (const float*)d_in[15];
    const float* normf_g = (const float*)d_in[16];
    const float* normf_b = (const float*)d_in[17];
    const float* fc2_w   = (const float*)d_in[18];
    const float* fc2_b   = (const float*)d_in[19];
    float* out = (float*)d_out;

    const int MROWS = B_SZ * NTOK;                          // 8194
    const int MT128 = (MROWS + 127) / 128;                  // 65
    const long XROW = (long)NTOK * DMODEL;                  // batch stride in x

    // ---- workspace layout ----
    char* p = (char*)d_ws;
    float* x   = (float*)p;            p += (long)B_SZ * NTOK * DMODEL * 4;
    float* pos = (float*)p;            p += (long)KLEN * DMODEL * 4;
    ushort_t* data_bf = (ushort_t*)p;  p += (long)B_SZ * 4096 * INDIM * 2;
    ushort_t* actA    = (ushort_t*)p;  p += (long)MROWS * DMODEL * 2;
    ushort_t* actB    = (ushort_t*)p;  p += (long)MROWS * DMODEL * 2;
    ushort_t* fc1_wt  = (ushort_t*)p;  p += (long)DMODEL * INDIM * 2;
    ushort_t* qkv_wt  = (ushort_t*)p;  p += (long)2 * 1536 * DMODEL * 2;
    ushort_t* out_wt  = (ushort_t*)p;  p += (long)2 * DMODEL * DMODEL * 2;
    ushort_t* ff1_wt  = (ushort_t*)p;  p += (long)2 * MLPD * DMODEL * 2;
    ushort_t* ff2_wt  = (ushort_t*)p;  p += (long)2 * DMODEL * MLPD * 2;
    ushort_t* qkv_bf  = (ushort_t*)p;                                   // [8194][1536]
    ushort_t* kf      = qkv_bf + (long)MROWS * 1536;                    // [2][4105][512]
    ushort_t* vt      = kf + (long)B_SZ * KLEN * DMODEL;                // [16][64][4160]
    ushort_t* ffbuf   = qkv_bf;                                         // overlays (layer-1 ff)

    // ---- one-time converts ----
    k_f2b<<<dim3(2048), dim3(256), 0, stream>>>(data, data_bf, (long)B_SZ * 4096 * INDIM / 4);
    k_w2bt<<<dim3(DMODEL/64, INDIM/64, 1),  dim3(256), 0, stream>>>(fc1_w, fc1_wt, INDIM, DMODEL);
    k_w2bt<<<dim3(1536/64, DMODEL/64, 2),   dim3(256), 0, stream>>>(qkv_w, qkv_wt, DMODEL, 1536);
    k_w2bt<<<dim3(DMODEL/64, DMODEL/64, 2), dim3(256), 0, stream>>>(out_w, out_wt, DMODEL, DMODEL);
    k_w2bt<<<dim3(MLPD/64, DMODEL/64, 2),   dim3(256), 0, stream>>>(ff_w1, ff1_wt, DMODEL, MLPD);
    k_w2bt<<<dim3(DMODEL/64, MLPD/64, 2),   dim3(256), 0, stream>>>(ff_w2, ff2_wt, MLPD, DMODEL);

    k_pos<<<dim3(KLEN), dim3(256), 0, stream>>>(pos);
    k_cls<<<dim3(B_SZ), dim3(512), 0, stream>>>(cls, x);

    // fc1 + ReLU -> x rows 1..4096 per batch (fp32 out)
    k_gemm_bf<EPI_BIAS_RELU, 0><<<dim3(DMODEL/128, 4096/128, B_SZ), dim3(256), 0, stream>>>(
        data_bf, fc1_wt, fc1_b, x + DMODEL, 4096, INDIM, DMODEL,
        (long)4096 * INDIM, XROW);

    // ================= layer 0 (full) =================
    {
        const int l = 0;
        k_ln<<<dim3(MROWS), dim3(256), 0, stream>>>(x, actA, ln1_g, ln1_b, 1);
        k_gemm_bf<EPI_NONE, 1><<<dim3(1536/128, MT128, 1), dim3(256), 0, stream>>>(
            actA, qkv_wt, nullptr, qkv_bf, MROWS, DMODEL, 1536, 0, 0);
        k_build_k <<<dim3((KLEN + 63)/64, B_SZ), dim3(256), 0, stream>>>(qkv_bf, mems, pos, kf, l);
        k_build_vt<<<dim3(KLEN_PAD/64, B_SZ, NHEAD), dim3(256), 0, stream>>>(qkv_bf, mems, pos, vt, l);
        k_attn_mfma<<<dim3((NTOK + 127)/128, NHEAD, B_SZ), dim3(256), 0, stream>>>(qkv_bf, kf, vt, actB);
        k_gemm_bf<EPI_BIAS_RES, 0><<<dim3(DMODEL/128, MT128, 1), dim3(256), 0, stream>>>(
            actB, out_wt, out_b, x, MROWS, DMODEL, DMODEL, 0, 0);
        k_ln<<<dim3(MROWS), dim3(256), 0, stream>>>(x, actA, ln2_g, ln2_b, 1);
        k_gemm_bf<EPI_BIAS_GELU, 1><<<dim3(MLPD/128, MT128, 1), dim3(256), 0, stream>>>(
            actA, ff1_wt, ff_b1, ffbuf, MROWS, DMODEL, MLPD, 0, 0);
        k_gemm_bf<EPI_BIAS_RES, 0><<<dim3(DMODEL/128, MT128, 1), dim3(256), 0, stream>>>(
            ffbuf, ff2_wt, ff_b2, x, MROWS, MLPD, DMODEL, 0, 0);
    }

    // ================= layer 1 (only cls row feeds the head) =================
    {
        const int l = 1;
        // K/V need all tokens -> full LN + qkv GEMM + builds
        k_ln<<<dim3(MROWS), dim3(256), 0, stream>>>(x, actA, ln1_g + DMODEL, ln1_b + DMODEL, 1);
        k_gemm_bf<EPI_NONE, 1><<<dim3(1536/128, MT128, 1), dim3(256), 0, stream>>>(
            actA, qkv_wt + (long)1536 * DMODEL, nullptr, qkv_bf, MROWS, DMODEL, 1536, 0, 0);
        k_build_k <<<dim3((KLEN + 63)/64, B_SZ), dim3(256), 0, stream>>>(qkv_bf, mems, pos, kf, l);
        k_build_vt<<<dim3(KLEN_PAD/64, B_SZ, NHEAD), dim3(256), 0, stream>>>(qkv_bf, mems, pos, vt, l);
        // attention: only q-tile 0 (contains the cls row)
        k_attn_mfma<<<dim3(1, NHEAD, B_SZ), dim3(256), 0, stream>>>(qkv_bf, kf, vt, actB);
        // out-proj on row 0 of each batch (A rows at b*NTOK in actB)
        k_gemm_bf<EPI_BIAS_RES, 0><<<dim3(DMODEL/128, 1, B_SZ), dim3(256), 0, stream>>>(
            actB, out_wt + (long)DMODEL * DMODEL, out_b + DMODEL, x, 1, DMODEL, DMODEL, XROW, XROW);
        // ln2 on the two cls rows (scattered at b*NTOK)
        k_ln<<<dim3(B_SZ), dim3(256), 0, stream>>>(x, actA, ln2_g + DMODEL, ln2_b + DMODEL, NTOK);
        // ff on row 0 per batch; ffbuf compact [B][MLPD]
        k_gemm_bf<EPI_BIAS_GELU, 1><<<dim3(MLPD/128, 1, B_SZ), dim3(256), 0, stream>>>(
            actA, ff1_wt + (long)MLPD * DMODEL, ff_b1 + MLPD, ffbuf, 1, DMODEL, MLPD, XROW, MLPD);
        k_gemm_bf<EPI_BIAS_RES, 0><<<dim3(DMODEL/128, 1, B_SZ), dim3(256), 0, stream>>>(
            ffbuf, ff2_wt + (long)DMODEL * MLPD, ff_b2 + DMODEL, x, 1, MLPD, DMODEL, MLPD, XROW);
    }

    k_final<<<dim3(B_SZ), dim3(256), 0, stream>>>(x, normf_g, normf_b, fc2_w, fc2_b, out);
}

// Round 6
// 969.568 us; speedup vs baseline: 5.0050x; 1.2307x over previous
//
#include <hip/hip_runtime.h>
#include <hip/hip_bf16.h>
#include <math.h>

// ---------------- problem constants ----------------
#define B_SZ   2
#define NTOK   4097      // n = 4096 + cls
#define KLEN   4105      // n + mem_len(8)
#define KLEN_PAD 4160    // 65 * 64
#define DMODEL 512
#define INDIM  1024
#define NHEAD  8
#define DHEAD  64
#define MLPD   2048
#define MEMLEN 8
#define NEG_BIG  -1.0e30f
#define CSCALE 0.18033688f   // (1/sqrt(64)) * log2(e); softmax runs in log2 domain

typedef unsigned short ushort_t;
typedef short bf16x8 __attribute__((ext_vector_type(8)));
typedef float f32x4  __attribute__((ext_vector_type(4)));

__device__ __forceinline__ unsigned short f2bf(float f) {
    union { float f; unsigned u; } v; v.f = f;
    const unsigned r = v.u + 0x7fff + ((v.u >> 16) & 1);   // RTNE
    return (unsigned short)(r >> 16);
}
__device__ __forceinline__ unsigned short f2bf_rhu(float f) {   // round-half-up (cheap, for P in [0,1])
    union { float f; unsigned u; } v; v.f = f;
    return (unsigned short)((v.u + 0x8000u) >> 16);
}
__device__ __forceinline__ float bf2f(unsigned short u) {
    union { unsigned u; float f; } v; v.u = ((unsigned)u) << 16;
    return v.f;
}

// async global->LDS, 16B per lane; lds base must be wave-uniform
__device__ __forceinline__ void gload_lds16(const void* g, void* l) {
    __builtin_amdgcn_global_load_lds(
        (const __attribute__((address_space(1))) unsigned int*)g,
        (__attribute__((address_space(3))) unsigned int*)l, 16, 0, 0);
}

// ---------------- small helpers ----------------
__device__ __forceinline__ float block_reduce_sum_256(float v, float* sh) {
    #pragma unroll
    for (int m = 1; m < 64; m <<= 1) v += __shfl_xor(v, m);
    const int w = threadIdx.x >> 6;
    if ((threadIdx.x & 63) == 0) sh[w] = v;
    __syncthreads();
    float r = sh[0] + sh[1] + sh[2] + sh[3];
    __syncthreads();
    return r;
}

// ---------------- pos emb (fast trig) ----------------
__global__ void k_pos(float* __restrict__ pos) {
    const int p = blockIdx.x;
    const int j = threadIdx.x;
    const float position = (float)(KLEN - 1 - p);
    const float inv_freq = exp2f(-(float)j * 0.051905126f);   // 10000^(-j/256)
    const float x = position * inv_freq;
    pos[(long)p * DMODEL + j]       = __sinf(x);
    pos[(long)p * DMODEL + 256 + j] = __cosf(x);
}

// ---------------- cls token ----------------
__global__ void k_cls(const float* __restrict__ cls, float* __restrict__ x) {
    const int b = blockIdx.x;
    x[(long)b * NTOK * DMODEL + threadIdx.x] = cls[threadIdx.x];
}

// ---------------- fp32 -> bf16 convert (grid-stride, float4) ----------------
__global__ __launch_bounds__(256)
void k_f2b(const float* __restrict__ in, ushort_t* __restrict__ out, long n4) {
    for (long i = blockIdx.x * 256 + threadIdx.x; i < n4; i += (long)gridDim.x * 256) {
        const float4 f = ((const float4*)in)[i];
        ushort4 u;
        u.x = f2bf(f.x); u.y = f2bf(f.y); u.z = f2bf(f.z); u.w = f2bf(f.w);
        ((ushort4*)out)[i] = u;
    }
}

// ---------------- weight fp32[K][N] -> bf16 Wt[N][K] (tiled transpose) ----------------
__global__ __launch_bounds__(256)
void k_w2bt(const float* __restrict__ W, ushort_t* __restrict__ Wt, int K, int N) {
    __shared__ float tile[64][65];
    W  += (long)blockIdx.z * K * N;
    Wt += (long)blockIdx.z * N * K;
    const int n0 = blockIdx.x * 64, k0 = blockIdx.y * 64;
    const int t = threadIdx.x;
    #pragma unroll
    for (int rep = 0; rep < 16; ++rep) {
        const int idx = rep * 256 + t;
        const int r = idx >> 6, c = idx & 63;
        tile[r][c] = W[(long)(k0 + r) * N + n0 + c];
    }
    __syncthreads();
    #pragma unroll
    for (int rep = 0; rep < 16; ++rep) {
        const int idx = rep * 256 + t;
        const int n = idx >> 6, kk = idx & 63;
        Wt[(long)(n0 + n) * K + k0 + kk] = f2bf(tile[kk][n]);
    }
}

// ---------------- bf16 MFMA GEMM: C[M,ldc] (+)= A[M,K] @ Wt[N,K]^T + epi ----------------
enum { EPI_NONE = 0, EPI_BIAS_RELU = 1, EPI_BIAS_GELU = 2, EPI_BIAS_RES = 3 };

template <int EPI, int OBF16>
__global__ __launch_bounds__(256)
void k_gemm_bf(const ushort_t* __restrict__ A, const ushort_t* __restrict__ Wt,
               const float* __restrict__ bias, void* __restrict__ Cv,
               int M, int K, int N, long ldc, long sAb, long sCb)
{
    __shared__ ushort_t As[128 * 64];
    __shared__ ushort_t Bs[128 * 64];
    const int t    = threadIdx.x;
    const int lane = t & 63;
    const int w    = t >> 6;
    const int l15  = lane & 15;
    const int lhi  = lane >> 4;
    const int wr   = w >> 1, wc = w & 1;
    const long bm = (long)blockIdx.y * 128, bn = (long)blockIdx.x * 128;
    A += (long)blockIdx.z * sAb;
    float*    Cf = (float*)Cv    + (long)blockIdx.z * sCb;
    ushort_t* Cb = (ushort_t*)Cv + (long)blockIdx.z * sCb;

    int srow[4], scol[4];
    #pragma unroll
    for (int i = 0; i < 4; ++i) {
        const int c = i * 256 + t;
        srow[i] = c >> 3;
        scol[i] = ((c & 7) ^ (srow[i] & 7)) << 3;
    }

    f32x4 acc[4][4] = {};

    for (int k0 = 0; k0 < K; k0 += 64) {
        __syncthreads();
        #pragma unroll
        for (int i = 0; i < 4; ++i) {
            long ar = bm + srow[i]; if (ar >= M) ar = M - 1;
            gload_lds16(A + ar * (long)K + k0 + scol[i],
                        &As[(i * 256 + (t & ~63)) * 8]);
        }
        #pragma unroll
        for (int i = 0; i < 4; ++i) {
            gload_lds16(Wt + (bn + srow[i]) * (long)K + k0 + scol[i],
                        &Bs[(i * 256 + (t & ~63)) * 8]);
        }
        asm volatile("s_waitcnt vmcnt(0)" ::: "memory");
        __syncthreads();

        #pragma unroll
        for (int ks = 0; ks < 2; ++ks) {
            bf16x8 af[4], bfr[4];
            #pragma unroll
            for (int m = 0; m < 4; ++m) {
                const int row = wr * 64 + m * 16 + l15;
                const int cb  = (ks * 64 + lhi * 16) ^ ((row & 7) << 4);
                af[m] = *(const bf16x8*)((const char*)As + row * 128 + cb);
            }
            #pragma unroll
            for (int n = 0; n < 4; ++n) {
                const int row = wc * 64 + n * 16 + l15;
                const int cb  = (ks * 64 + lhi * 16) ^ ((row & 7) << 4);
                bfr[n] = *(const bf16x8*)((const char*)Bs + row * 128 + cb);
            }
            #pragma unroll
            for (int m = 0; m < 4; ++m)
                #pragma unroll
                for (int n = 0; n < 4; ++n)
                    acc[m][n] = __builtin_amdgcn_mfma_f32_16x16x32_bf16(af[m], bfr[n], acc[m][n], 0, 0, 0);
        }
    }

    #pragma unroll
    for (int m = 0; m < 4; ++m) {
        #pragma unroll
        for (int j = 0; j < 4; ++j) {
            const long mg = bm + wr * 64 + m * 16 + lhi * 4 + j;
            if (mg < M) {
                #pragma unroll
                for (int n = 0; n < 4; ++n) {
                    const long ng = bn + wc * 64 + n * 16 + l15;
                    float r = acc[m][n][j];
                    if (EPI != EPI_NONE) r += bias[ng];
                    if (EPI == EPI_BIAS_RELU) r = fmaxf(r, 0.f);
                    if (EPI == EPI_BIAS_GELU) r = 0.5f * r * (1.f + erff(r * 0.70710678118654752f));
                    if (OBF16) Cb[mg * ldc + ng] = f2bf(r);
                    else if (EPI == EPI_BIAS_RES) Cf[mg * ldc + ng] += r;
                    else Cf[mg * ldc + ng] = r;
                }
            }
        }
    }
}

// ---------------- GEMV (M=1 per batch): out[n] = A_row . Wt[n] + epi ----------------
template <int EPI, int OBF16>
__global__ __launch_bounds__(256)
void k_gemv(const ushort_t* __restrict__ A, const ushort_t* __restrict__ Wt,
            const float* __restrict__ bias, void* __restrict__ Cv,
            int K, int N, long sA, long sC)
{
    const int b = blockIdx.y;
    const int n = blockIdx.x * 64 + (threadIdx.x >> 2);
    const int j = threadIdx.x & 3;
    const ushort_t* a = A + (long)b * sA;
    const ushort_t* wv = Wt + (long)n * K;
    float sum = 0.f;
    for (int k0 = j * 8; k0 < K; k0 += 32) {
        const bf16x8 av = *(const bf16x8*)(a + k0);
        const bf16x8 wr = *(const bf16x8*)(wv + k0);
        #pragma unroll
        for (int e = 0; e < 8; ++e)
            sum += bf2f((ushort_t)av[e]) * bf2f((ushort_t)wr[e]);
    }
    sum += __shfl_xor(sum, 1);
    sum += __shfl_xor(sum, 2);
    if (j == 0 && n < N) {
        float r = sum;
        if (EPI != EPI_NONE) r += bias[n];
        if (EPI == EPI_BIAS_GELU) r = 0.5f * r * (1.f + erff(r * 0.70710678118654752f));
        if (OBF16) ((ushort_t*)Cv)[(long)b * sC + n] = f2bf(r);
        else if (EPI == EPI_BIAS_RES) ((float*)Cv)[(long)b * sC + n] += r;
        else ((float*)Cv)[(long)b * sC + n] = r;
    }
}

// ---------------- LayerNorm over rows of 512, bf16 out; rstride picks rows ----------------
__global__ __launch_bounds__(256)
void k_ln(const float* __restrict__ x, ushort_t* __restrict__ y,
          const float* __restrict__ g, const float* __restrict__ b, long rstride)
{
    __shared__ float sh[4];
    const long row = (long)blockIdx.x * rstride;
    const float* xr = x + row * DMODEL;
    const int t = threadIdx.x;
    const float v0 = xr[t], v1 = xr[t + 256];
    const float s  = block_reduce_sum_256(v0 + v1, sh);
    const float s2 = block_reduce_sum_256(v0 * v0 + v1 * v1, sh);
    const float mu = s * (1.f / DMODEL);
    const float var = s2 * (1.f / DMODEL) - mu * mu;
    const float rs = rsqrtf(var + 1e-5f);
    y[row * DMODEL + t]       = f2bf((v0 - mu) * rs * g[t] + b[t]);
    y[row * DMODEL + t + 256] = f2bf((v1 - mu) * rs * g[t + 256] + b[t + 256]);
}

// ---------------- build bf16 K rows (pre-scaled by CSCALE): [b][klen][512] ----------------
__global__ __launch_bounds__(256)
void k_build_k(const ushort_t* __restrict__ qkvb, const float* __restrict__ mems,
               const float* __restrict__ pos, ushort_t* __restrict__ kf, int layer)
{
    const int b = blockIdx.y;
    const long idx = (long)blockIdx.x * 256 + threadIdx.x;   // over KLEN*128
    const int j  = (int)(idx >> 7);
    const int d0 = (int)(idx & 127) * 4;
    if (j >= KLEN) return;
    float v0, v1, v2, v3;
    if (j < NTOK) {
        const ushort_t* s = qkvb + ((long)b * NTOK + j) * 1536 + 512 + d0;
        v0 = bf2f(s[0]); v1 = bf2f(s[1]); v2 = bf2f(s[2]); v3 = bf2f(s[3]);
    } else {
        const float* mb = mems + (((long)layer * B_SZ + b) * MEMLEN + (j - NTOK)) * DMODEL + d0;
        v0 = mb[0]; v1 = mb[1]; v2 = mb[2]; v3 = mb[3];
    }
    const float4 pe = *(const float4*)(pos + (long)j * DMODEL + d0);
    ushort4 o;
    o.x = f2bf((v0 + pe.x) * CSCALE);
    o.y = f2bf((v1 + pe.y) * CSCALE);
    o.z = f2bf((v2 + pe.z) * CSCALE);
    o.w = f2bf((v3 + pe.w) * CSCALE);
    *(ushort4*)(kf + ((long)b * KLEN + j) * DMODEL + d0) = o;
}

// ---------------- build bf16 V transposed: [b*8+h][d=64][KLEN_PAD] ----------------
__global__ __launch_bounds__(256)
void k_build_vt(const ushort_t* __restrict__ qkvb, const float* __restrict__ mems,
                const float* __restrict__ pos, ushort_t* __restrict__ vt, int layer)
{
    __shared__ ushort_t tile[64][65];
    const int jb = blockIdx.x * 64;
    const int b  = blockIdx.y;
    const int h  = blockIdx.z;
    const int t  = threadIdx.x;
    #pragma unroll
    for (int rep = 0; rep < 16; ++rep) {
        const int idx = rep * 256 + t;
        const int r = idx >> 6, c = idx & 63;
        const int j = jb + r;
        float val = 0.f;
        if (j < NTOK)
            val = bf2f(qkvb[((long)b * NTOK + j) * 1536 + 1024 + h * 64 + c]) + pos[(long)j * DMODEL + h * 64 + c];
        else if (j < KLEN)
            val = mems[(((long)layer * B_SZ + b) * MEMLEN + (j - NTOK)) * DMODEL + h * 64 + c]
                + pos[(long)j * DMODEL + h * 64 + c];
        tile[c][r] = f2bf(val);
    }
    __syncthreads();
    #pragma unroll
    for (int rep = 0; rep < 16; ++rep) {
        const int idx = rep * 256 + t;
        const int d = idx >> 6, r = idx & 63;
        vt[(((long)b * NHEAD + h) * 64 + d) * (long)KLEN_PAD + jb + r] = tile[d][r];
    }
}

// ---------------- MFMA flash attention: 64-query tile, reg-prefetch pipeline ----------------
#define LDSP 72

__global__ __launch_bounds__(256)
void k_attn_mfma(const ushort_t* __restrict__ qkvb,
                 const ushort_t* __restrict__ kf,
                 const ushort_t* __restrict__ vt,
                 ushort_t* __restrict__ outp)
{
    __shared__ ushort_t QPs[64][LDSP];  // Q at start, then reused as P
    __shared__ ushort_t Ks [64][LDSP];
    __shared__ ushort_t Vts[64][LDSP];

    const int t    = threadIdx.x;
    const int lane = t & 63;
    const int w    = t >> 6;
    const int l15  = lane & 15;
    const int lhi  = lane >> 4;
    const int qb   = blockIdx.x * 64;
    const int h    = blockIdx.y;
    const int b    = blockIdx.z;

    // ---- stage Q (bf16 direct copy) ----
    {
        const int r  = t >> 2;
        const int c0 = (t & 3) * 16;
        const int qg = qb + r;
        uint4 u0 = make_uint4(0,0,0,0), u1 = make_uint4(0,0,0,0);
        if (qg < NTOK) {
            const ushort_t* src = qkvb + ((long)b * NTOK + qg) * 1536 + h * 64 + c0;
            u0 = ((const uint4*)src)[0];
            u1 = ((const uint4*)src)[1];
        }
        *(uint4*)&QPs[r][c0]     = u0;
        *(uint4*)&QPs[r][c0 + 8] = u1;
    }

    const ushort_t* kbase = kf + (long)b * KLEN * DMODEL + h * 64;
    const ushort_t* vbase = vt + ((long)b * NHEAD + h) * 64 * (long)KLEN_PAD;
    const int rr  = t >> 2;
    const int c80 = (t & 3) * 2;

    uint4 kreg[2], vreg[2];
    // prefetch tile 0
    #pragma unroll
    for (int cc = 0; cc < 2; ++cc) {
        const int c8 = c80 + cc;
        kreg[cc] = make_uint4(0u, 0u, 0u, 0u);
        if (rr < KLEN) kreg[cc] = *(const uint4*)(kbase + (long)rr * DMODEL + c8 * 8);
        vreg[cc] = *(const uint4*)(vbase + (long)rr * KLEN_PAD + c8 * 8);
    }

    __syncthreads();   // Q staged
    bf16x8 q_frag[2];
    #pragma unroll
    for (int ks = 0; ks < 2; ++ks)
        q_frag[ks] = *(const bf16x8*)&QPs[w * 16 + l15][ks * 32 + lhi * 8];

    // store tile 0
    #pragma unroll
    for (int cc = 0; cc < 2; ++cc) {
        *(uint4*)&Ks [rr][(c80 + cc) * 8] = kreg[cc];
        *(uint4*)&Vts[rr][(c80 + cc) * 8] = vreg[cc];
    }
    __syncthreads();

    f32x4 o_frag[4] = {};
    float m_run[4] = {NEG_BIG, NEG_BIG, NEG_BIG, NEG_BIG};
    float l_run[4] = {0.f, 0.f, 0.f, 0.f};

    for (int kt = 0; kt <= 64; ++kt) {
        const int kb = kt * 64;
        // ---- issue prefetch of next tile (clamped; tail reload is harmless) ----
        const int kbn = (kt < 64) ? kb + 64 : kb;
        {
            const int jg = kbn + rr;
            #pragma unroll
            for (int cc = 0; cc < 2; ++cc) {
                const int c8 = c80 + cc;
                kreg[cc] = make_uint4(0u, 0u, 0u, 0u);
                if (jg < KLEN) kreg[cc] = *(const uint4*)(kbase + (long)jg * DMODEL + c8 * 8);
                vreg[cc] = *(const uint4*)(vbase + (long)rr * KLEN_PAD + kbn + c8 * 8);
            }
        }
        __builtin_amdgcn_sched_barrier(0);   // pin load issue before compute

        // ---- S = Q @ K^T (log2-scaled domain; scale folded into K) ----
        f32x4 s_frag[4];
        __builtin_amdgcn_s_setprio(1);
        #pragma unroll
        for (int n = 0; n < 4; ++n) {
            f32x4 acc = {0.f, 0.f, 0.f, 0.f};
            #pragma unroll
            for (int ks = 0; ks < 2; ++ks) {
                const bf16x8 kfr = *(const bf16x8*)&Ks[n * 16 + l15][ks * 32 + lhi * 8];
                acc = __builtin_amdgcn_mfma_f32_16x16x32_bf16(q_frag[ks], kfr, acc, 0, 0, 0);
            }
            s_frag[n] = acc;
        }
        __builtin_amdgcn_s_setprio(0);

        // ---- online softmax (exp2); mask only in tail tile ----
        #pragma unroll
        for (int i = 0; i < 4; ++i) {
            float sv[4];
            #pragma unroll
            for (int n = 0; n < 4; ++n) sv[n] = s_frag[n][i];
            if (kt == 64) {
                #pragma unroll
                for (int n = 0; n < 4; ++n)
                    if (kb + n * 16 + l15 >= KLEN) sv[n] = NEG_BIG;
            }
            float mx = fmaxf(fmaxf(sv[0], sv[1]), fmaxf(sv[2], sv[3]));
            mx = fmaxf(mx, __shfl_xor(mx, 1));
            mx = fmaxf(mx, __shfl_xor(mx, 2));
            mx = fmaxf(mx, __shfl_xor(mx, 4));
            mx = fmaxf(mx, __shfl_xor(mx, 8));
            const float mnew  = fmaxf(m_run[i], mx);
            const float alpha = exp2f(m_run[i] - mnew);
            float lsum = 0.f;
            ushort_t pb[4];
            #pragma unroll
            for (int n = 0; n < 4; ++n) {
                const float p = exp2f(sv[n] - mnew);
                lsum += p;
                pb[n] = f2bf_rhu(p);
            }
            lsum += __shfl_xor(lsum, 1);
            lsum += __shfl_xor(lsum, 2);
            lsum += __shfl_xor(lsum, 4);
            lsum += __shfl_xor(lsum, 8);
            l_run[i] = l_run[i] * alpha + lsum;
            m_run[i] = mnew;
            #pragma unroll
            for (int n = 0; n < 4; ++n) {
                o_frag[n][i] *= alpha;
                QPs[w * 16 + lhi * 4 + i][n * 16 + l15] = pb[n];   // wave-private strip
            }
        }
        // no barrier: P strip is wave-private; LDS ops are in-order within a wave

        // ---- O += P @ V ----
        __builtin_amdgcn_s_setprio(1);
        #pragma unroll
        for (int n = 0; n < 4; ++n) {
            #pragma unroll
            for (int ks = 0; ks < 2; ++ks) {
                const bf16x8 pa = *(const bf16x8*)&QPs[w * 16 + l15][ks * 32 + lhi * 8];
                const bf16x8 vb = *(const bf16x8*)&Vts[n * 16 + l15][ks * 32 + lhi * 8];
                o_frag[n] = __builtin_amdgcn_mfma_f32_16x16x32_bf16(pa, vb, o_frag[n], 0, 0, 0);
            }
        }
        __builtin_amdgcn_s_setprio(0);

        __syncthreads();   // all waves done reading Ks/Vts of tile kt
        #pragma unroll
        for (int cc = 0; cc < 2; ++cc) {
            *(uint4*)&Ks [rr][(c80 + cc) * 8] = kreg[cc];
            *(uint4*)&Vts[rr][(c80 + cc) * 8] = vreg[cc];
        }
        __syncthreads();   // next tile visible
    }

    // ---- epilogue ----
    #pragma unroll
    for (int i = 0; i < 4; ++i) {
        const int rg = qb + w * 16 + lhi * 4 + i;
        if (rg < NTOK) {
            const float inv = 1.f / l_run[i];
            ushort_t* op = outp + ((long)b * NTOK + rg) * DMODEL + h * 64 + l15;
            #pragma unroll
            for (int n = 0; n < 4; ++n) op[n * 16] = f2bf(o_frag[n][i] * inv);
        }
    }
}

// ---------------- final LN + 2-class head on cls row ----------------
__global__ __launch_bounds__(256)
void k_final(const float* __restrict__ x, const float* __restrict__ g,
             const float* __restrict__ bb, const float* __restrict__ w2,
             const float* __restrict__ b2, float* __restrict__ out)
{
    __shared__ float sh[4];
    const int b = blockIdx.x;
    const float* xr = x + (long)b * NTOK * DMODEL;
    const int t = threadIdx.x;
    const float v0 = xr[t], v1 = xr[t + 256];
    const float s  = block_reduce_sum_256(v0 + v1, sh);
    const float s2 = block_reduce_sum_256(v0 * v0 + v1 * v1, sh);
    const float mu = s * (1.f / DMODEL);
    const float var = s2 * (1.f / DMODEL) - mu * mu;
    const float rs = rsqrtf(var + 1e-5f);
    const float n0 = (v0 - mu) * rs * g[t] + bb[t];
    const float n1 = (v1 - mu) * rs * g[t + 256] + bb[t + 256];
    const float p0 = block_reduce_sum_256(n0 * w2[t * 2 + 0] + n1 * w2[(t + 256) * 2 + 0], sh);
    const float p1 = block_reduce_sum_256(n0 * w2[t * 2 + 1] + n1 * w2[(t + 256) * 2 + 1], sh);
    if (t == 0) {
        out[b * 2 + 0] = p0 + b2[0];
        out[b * 2 + 1] = p1 + b2[1];
    }
}

// ---------------- host orchestration ----------------
extern "C" void kernel_launch(void* const* d_in, const int* in_sizes, int n_in,
                              void* d_out, int out_size, void* d_ws, size_t ws_size,
                              hipStream_t stream)
{
    const float* data    = (const float*)d_in[0];
    const float* mems    = (const float*)d_in[1];
    const float* fc1_w   = (const float*)d_in[2];
    const float* fc1_b   = (const float*)d_in[3];
    const float* cls     = (const float*)d_in[4];
    const float* ln1_g   = (const float*)d_in[5];
    const float* ln1_b   = (const float*)d_in[6];
    const float* qkv_w   = (const float*)d_in[7];
    const float* out_w   = (const float*)d_in[8];
    const float* out_b   = (const float*)d_in[9];
    const float* ln2_g   = (const float*)d_in[10];
    const float* ln2_b   = (const float*)d_in[11];
    const float* ff_w1   = (const float*)d_in[12];
    const float* ff_b1   = (const float*)d_in[13];
    const float* ff_w2   = (const float*)d_in[14];
    const float* ff_b2   = (const float*)d_in[15];
    const float* normf_g = (const float*)d_in[16];
    const float* normf_b = (const float*)d_in[17];
    const float* fc2_w   = (const float*)d_in[18];
    const float* fc2_b   = (const float*)d_in[19];
    float* out = (float*)d_out;

    const int MROWS = B_SZ * NTOK;                          // 8194
    const int MT128 = (MROWS + 127) / 128;                  // 65
    const long XROW = (long)NTOK * DMODEL;                  // batch stride in x

    // ---- workspace layout ----
    char* p = (char*)d_ws;
    float* x   = (float*)p;            p += (long)B_SZ * NTOK * DMODEL * 4;
    float* pos = (float*)p;            p += (long)KLEN * DMODEL * 4;
    ushort_t* data_bf = (ushort_t*)p;  p += (long)B_SZ * 4096 * INDIM * 2;
    ushort_t* actA    = (ushort_t*)p;  p += (long)MROWS * DMODEL * 2;
    ushort_t* actB    = (ushort_t*)p;  p += (long)MROWS * DMODEL * 2;
    ushort_t* fc1_wt  = (ushort_t*)p;  p += (long)DMODEL * INDIM * 2;
    ushort_t* qkv_wt  = (ushort_t*)p;  p += (long)2 * 1536 * DMODEL * 2;
    ushort_t* out_wt  = (ushort_t*)p;  p += (long)2 * DMODEL * DMODEL * 2;
    ushort_t* ff1_wt  = (ushort_t*)p;  p += (long)2 * MLPD * DMODEL * 2;
    ushort_t* ff2_wt  = (ushort_t*)p;  p += (long)2 * DMODEL * MLPD * 2;
    ushort_t* qkv_bf  = (ushort_t*)p;                                   // [8194][1536]
    ushort_t* kf      = qkv_bf + (long)MROWS * 1536;                    // [2][4105][512]
    ushort_t* vt      = kf + (long)B_SZ * KLEN * DMODEL;                // [16][64][4160]
    ushort_t* ffbuf   = qkv_bf;                                         // overlays

    // ---- one-time converts ----
    k_f2b<<<dim3(2048), dim3(256), 0, stream>>>(data, data_bf, (long)B_SZ * 4096 * INDIM / 4);
    k_w2bt<<<dim3(DMODEL/64, INDIM/64, 1),  dim3(256), 0, stream>>>(fc1_w, fc1_wt, INDIM, DMODEL);
    k_w2bt<<<dim3(1536/64, DMODEL/64, 2),   dim3(256), 0, stream>>>(qkv_w, qkv_wt, DMODEL, 1536);
    k_w2bt<<<dim3(DMODEL/64, DMODEL/64, 2), dim3(256), 0, stream>>>(out_w, out_wt, DMODEL, DMODEL);
    k_w2bt<<<dim3(MLPD/64, DMODEL/64, 2),   dim3(256), 0, stream>>>(ff_w1, ff1_wt, DMODEL, MLPD);
    k_w2bt<<<dim3(DMODEL/64, MLPD/64, 2),   dim3(256), 0, stream>>>(ff_w2, ff2_wt, MLPD, DMODEL);

    k_pos<<<dim3(KLEN), dim3(256), 0, stream>>>(pos);
    k_cls<<<dim3(B_SZ), dim3(512), 0, stream>>>(cls, x);

    // fc1 + ReLU -> x rows 1..4096 per batch (fp32 out)
    k_gemm_bf<EPI_BIAS_RELU, 0><<<dim3(DMODEL/128, 4096/128, B_SZ), dim3(256), 0, stream>>>(
        data_bf, fc1_wt, fc1_b, x + DMODEL, 4096, INDIM, DMODEL, DMODEL,
        (long)4096 * INDIM, XROW);

    const int KBK = (KLEN * 128 + 255) / 256;   // build_k blocks per batch

    // ================= layer 0 (full) =================
    {
        k_ln<<<dim3(MROWS), dim3(256), 0, stream>>>(x, actA, ln1_g, ln1_b, 1);
        k_gemm_bf<EPI_NONE, 1><<<dim3(1536/128, MT128, 1), dim3(256), 0, stream>>>(
            actA, qkv_wt, nullptr, qkv_bf, MROWS, DMODEL, 1536, 1536, 0, 0);
        k_build_k <<<dim3(KBK, B_SZ), dim3(256), 0, stream>>>(qkv_bf, mems, pos, kf, 0);
        k_build_vt<<<dim3(KLEN_PAD/64, B_SZ, NHEAD), dim3(256), 0, stream>>>(qkv_bf, mems, pos, vt, 0);
        k_attn_mfma<<<dim3((NTOK + 63)/64, NHEAD, B_SZ), dim3(256), 0, stream>>>(qkv_bf, kf, vt, actB);
        k_gemm_bf<EPI_BIAS_RES, 0><<<dim3(DMODEL/128, MT128, 1), dim3(256), 0, stream>>>(
            actB, out_wt, out_b, x, MROWS, DMODEL, DMODEL, DMODEL, 0, 0);
        k_ln<<<dim3(MROWS), dim3(256), 0, stream>>>(x, actA, ln2_g, ln2_b, 1);
        k_gemm_bf<EPI_BIAS_GELU, 1><<<dim3(MLPD/128, MT128, 1), dim3(256), 0, stream>>>(
            actA, ff1_wt, ff_b1, ffbuf, MROWS, DMODEL, MLPD, MLPD, 0, 0);
        k_gemm_bf<EPI_BIAS_RES, 0><<<dim3(DMODEL/128, MT128, 1), dim3(256), 0, stream>>>(
            ffbuf, ff2_wt, ff_b2, x, MROWS, MLPD, DMODEL, DMODEL, 0, 0);
    }

    // ================= layer 1 (only cls row feeds the head) =================
    {
        // K/V need all tokens -> full LN + KV-only GEMM (N=1024, cols 512..1535)
        k_ln<<<dim3(MROWS), dim3(256), 0, stream>>>(x, actA, ln1_g + DMODEL, ln1_b + DMODEL, 1);
        k_gemm_bf<EPI_NONE, 1><<<dim3(1024/128, MT128, 1), dim3(256), 0, stream>>>(
            actA, qkv_wt + (long)1536 * DMODEL + (long)512 * DMODEL, nullptr, qkv_bf + 512,
            MROWS, DMODEL, 1024, 1536, 0, 0);
        // Q for the cls row only (per batch) -> qkv_bf row b*NTOK, cols 0..511
        k_gemv<EPI_NONE, 1><<<dim3(512/64, B_SZ), dim3(256), 0, stream>>>(
            actA, qkv_wt + (long)1536 * DMODEL, nullptr, qkv_bf,
            DMODEL, 512, (long)NTOK * DMODEL, (long)NTOK * 1536);
        k_build_k <<<dim3(KBK, B_SZ), dim3(256), 0, stream>>>(qkv_bf, mems, pos, kf, 1);
        k_build_vt<<<dim3(KLEN_PAD/64, B_SZ, NHEAD), dim3(256), 0, stream>>>(qkv_bf, mems, pos, vt, 1);
        // attention: only q-tile 0 (contains the cls row)
        k_attn_mfma<<<dim3(1, NHEAD, B_SZ), dim3(256), 0, stream>>>(qkv_bf, kf, vt, actB);
        // out-proj on cls row per batch
        k_gemv<EPI_BIAS_RES, 0><<<dim3(512/64, B_SZ), dim3(256), 0, stream>>>(
            actB, out_wt + (long)DMODEL * DMODEL, out_b + DMODEL, x,
            DMODEL, 512, (long)NTOK * DMODEL, XROW);
        // ln2 on the two cls rows
        k_ln<<<dim3(B_SZ), dim3(256), 0, stream>>>(x, actA, ln2_g + DMODEL, ln2_b + DMODEL, NTOK);
        // ff on cls row per batch
        k_gemv<EPI_BIAS_GELU, 1><<<dim3(MLPD/64, B_SZ), dim3(256), 0, stream>>>(
            actA, ff1_wt + (long)MLPD * DMODEL, ff_b1 + MLPD, ffbuf,
            DMODEL, MLPD, (long)NTOK * DMODEL, MLPD);
        k_gemv<EPI_BIAS_RES, 0><<<dim3(512/64, B_SZ), dim3(256), 0, stream>>>(
            ffbuf, ff2_wt + (long)DMODEL * MLPD, ff_b2 + DMODEL, x,
            MLPD, 512, MLPD, XROW);
    }

    k_final<<<dim3(B_SZ), dim3(256), 0, stream>>>(x, normf_g, normf_b, fc2_w, fc2_b, out);
}